// Round 9
// baseline (1379.524 us; speedup 1.0000x reference)
//
#include <hip/hip_runtime.h>
#include <math.h>
#include <stdint.h>

#define NPTS 8192
#define FIN 512
#define FHID 512
#define FOUT 256
#define NCLU 10
#define KNEI 10
#define GAMMA_F 2.0f
#define LISTCAP 4160   // > 4096 direct cap and > 4095 complement cap

typedef __attribute__((ext_vector_type(4))) float f32x4;
typedef __attribute__((ext_vector_type(8))) short bf16x8;

// ---------------- sum of squares per row ----------------
__global__ void k_sumsq(const float* __restrict__ x, float* __restrict__ sq) {
    int row = blockIdx.x;
    const float* xr = x + (size_t)row * FIN;
    float s = 0.f;
    for (int k = threadIdx.x; k < FIN; k += 256) s += xr[k] * xr[k];
    __shared__ float red[256];
    red[threadIdx.x] = s; __syncthreads();
    for (int off = 128; off > 0; off >>= 1) {
        if (threadIdx.x < off) red[threadIdx.x] += red[threadIdx.x + off];
        __syncthreads();
    }
    if (threadIdx.x == 0) sq[row] = red[0];
}

// ---------------- f32 -> bf16 (RNE) ----------------
__global__ void k_tobf16(const float* __restrict__ x, unsigned short* __restrict__ xb) {
    int i = blockIdx.x * 256 + threadIdx.x;   // one float4 per thread
    f32x4 v = reinterpret_cast<const f32x4*>(x)[i];
    ushort4 o;
    #pragma unroll
    for (int e = 0; e < 4; e++) {
        union { float f; unsigned u; } cvt; cvt.f = v[e];
        unsigned r = (cvt.u + 0x7FFFu + ((cvt.u >> 16) & 1u)) >> 16;
        ((unsigned short*)&o)[e] = (unsigned short)r;
    }
    reinterpret_cast<ushort4*>(xb)[i] = o;
}

// ---------------- fused MFMA gram + exp + per-row partial top-10 ----------------
// grid: 2048 = 512 row-groups x 4 col-chunks. block b: rg=b>>2 (16 rows), ch=b&3
// (4 tiles of 512 cols). ch == b%4 is constant per XCD (round-robin %8) -> each
// XCD's B-working-set is one 2MB chunk of xb -> L2-resident.
#define GR_ROWS 16
#define GR_BN 512
#define GR_CHUNKS 4
#define GR_CT (NPTS / GR_BN / GR_CHUNKS)   // 4 tiles per chunk

__global__ __launch_bounds__(256, 4) void k_gram_topk(
    const unsigned short* __restrict__ xb, const float* __restrict__ sq,
    float* __restrict__ tpv, int* __restrict__ tpi)
{
    __shared__ float Sl[GR_ROWS][GR_BN + 1];
    __shared__ float tval[GR_ROWS][KNEI];
    __shared__ int   tidxs[GR_ROWS][KNEI];

    const int tid  = threadIdx.x;
    const int lane = tid & 63;
    const int wv   = tid >> 6;            // 0..3
    const int rg   = blockIdx.x >> 2;
    const int ch   = blockIdx.x & 3;
    const int r0   = rg * GR_ROWS;

    if (tid < GR_ROWS * KNEI) {
        tval[tid / KNEI][tid % KNEI] = -INFINITY;
        tidxs[tid / KNEI][tid % KNEI] = 0x7fffffff;
    }
    __syncthreads();

    const int arow  = r0 + (lane & 15);
    const int akoff = (lane >> 4) * 8;
    bf16x8 afr[16];
    #pragma unroll
    for (int ks = 0; ks < 16; ks++)
        afr[ks] = *reinterpret_cast<const bf16x8*>(xb + (size_t)arow * FIN + ks * 32 + akoff);

    float si_r[4];
    #pragma unroll
    for (int r = 0; r < 4; r++) si_r[r] = sq[r0 + (lane >> 4) * 4 + r];

    for (int t = ch * GR_CT; t < (ch + 1) * GR_CT; ++t) {
        const int c0 = t * GR_BN + wv * 128;
        f32x4 acc[8];
        #pragma unroll
        for (int ct = 0; ct < 8; ct++) acc[ct] = (f32x4){0.f, 0.f, 0.f, 0.f};

        #pragma unroll
        for (int ks = 0; ks < 16; ks++) {
            #pragma unroll
            for (int ct = 0; ct < 8; ct++) {
                const int j = c0 + ct * 16 + (lane & 15);
                bf16x8 bfr = *reinterpret_cast<const bf16x8*>(xb + (size_t)j * FIN + ks * 32 + akoff);
                acc[ct] = __builtin_amdgcn_mfma_f32_16x16x32_bf16(afr[ks], bfr, acc[ct], 0, 0, 0);
            }
        }

        #pragma unroll
        for (int ct = 0; ct < 8; ct++) {
            const int col = wv * 128 + ct * 16 + (lane & 15);
            const int gj  = t * GR_BN + col;
            const float sjv = sq[gj];
            #pragma unroll
            for (int r = 0; r < 4; r++) {
                const int row = (lane >> 4) * 4 + r;
                const int gi  = r0 + row;
                const float d2 = si_r[r] + sjv - 2.f * acc[ct][r];
                Sl[row][col] = (gj == gi) ? -INFINITY : expf(-d2 * 0.5f);
            }
        }
        __syncthreads();

        for (int q = 0; q < 4; ++q) {
            int r = wv * 4 + q;
            for (int base = 0; base < GR_BN; base += 64) {
                float v = Sl[r][base + lane];
                int gj = t * GR_BN + base + lane;
                float rv9 = tval[r][KNEI - 1];
                int ri9 = tidxs[r][KNEI - 1];
                unsigned long long bal = __ballot(v > rv9 || (v == rv9 && gj < ri9));
                if (lane == 0 && bal) {
                    while (bal) {
                        int l = __ffsll((unsigned long long)bal) - 1;
                        bal &= bal - 1;
                        float cv = Sl[r][base + l];
                        int cj = t * GR_BN + base + l;
                        float a9 = tval[r][KNEI - 1];
                        int i9 = tidxs[r][KNEI - 1];
                        if (cv > a9 || (cv == a9 && cj < i9)) {
                            int pp = KNEI - 1;
                            tval[r][pp] = cv; tidxs[r][pp] = cj;
                            while (pp > 0) {
                                float pv = tval[r][pp - 1]; int pi = tidxs[r][pp - 1];
                                if (cv > pv || (cv == pv && cj < pi)) {
                                    tval[r][pp] = pv; tidxs[r][pp] = pi;
                                    tval[r][pp - 1] = cv; tidxs[r][pp - 1] = cj;
                                    --pp;
                                } else break;
                            }
                        }
                    }
                }
            }
        }
        __syncthreads();
    }

    if (tid < GR_ROWS * KNEI) {
        int r = tid / KNEI, m = tid % KNEI;
        size_t o = (((size_t)(r0 + r) * GR_CHUNKS) + ch) * KNEI + m;
        tpv[o] = tval[r][m];
        tpi[o] = tidxs[r][m];
    }
}

// ---------------- merge 4 partial top-10 lists per row ----------------
__global__ __launch_bounds__(256) void k_topk_merge(const float* __restrict__ tpv,
        const int* __restrict__ tpi, int* __restrict__ topidx) {
    int r = blockIdx.x * 256 + threadIdx.x;
    int p[GR_CHUNKS] = {0, 0, 0, 0};
    #pragma unroll
    for (int m = 0; m < KNEI; m++) {
        float bv = -INFINITY; int bi = 0x7fffffff; int bc = 0;
        #pragma unroll
        for (int c = 0; c < GR_CHUNKS; c++) {
            if (p[c] < KNEI) {
                size_t o = (((size_t)r * GR_CHUNKS) + c) * KNEI + p[c];
                float v = tpv[o];
                int idx = tpi[o];
                if (v > bv || (v == bv && idx < bi)) { bv = v; bi = idx; bc = c; }
            }
        }
        topidx[(size_t)r * KNEI + m] = bi;
        p[bc]++;
    }
}

// ---------------- build symmetric adjacency bitmask ----------------
__global__ void k_set_edges(const int* __restrict__ topidx, unsigned int* __restrict__ mask) {
    int t = blockIdx.x * 256 + threadIdx.x;
    if (t >= NPTS * KNEI) return;
    int i = t / KNEI;
    int j = topidx[t];
    atomicOr(&mask[(size_t)i * (NPTS / 32) + (j >> 5)], 1u << (j & 31));
    atomicOr(&mask[(size_t)j * (NPTS / 32) + (i >> 5)], 1u << (i & 31));
}

// ---------------- degree, inv ----------------
__global__ void k_degree(const unsigned int* __restrict__ mask, float* __restrict__ degf,
                         float* __restrict__ inv) {
    int i = blockIdx.x, lane = threadIdx.x;  // 64 threads
    int c = 0;
    for (int w = lane; w < NPTS / 32; w += 64) c += __popc(mask[(size_t)i * (NPTS / 32) + w]);
    for (int off = 32; off > 0; off >>= 1) c += __shfl_xor(c, off);
    if (lane == 0) {
        float d = (float)c;
        degf[i] = d;
        inv[i] = (c > 0) ? 1.0f / d : 0.0f;
    }
}

// ---------------- generic f32 GEMM ----------------
__global__ __launch_bounds__(256) void k_gemm(const float* __restrict__ A, const float* __restrict__ B,
                                              float* __restrict__ C, int M, int Kd, int Nd) {
    __shared__ float Al[64][17];
    __shared__ float Bl[16][65];
    int tid = threadIdx.x;
    int bx = blockIdx.x, by = blockIdx.y;
    int tx = tid & 15, ty = tid >> 4;
    float acc[4][4];
    #pragma unroll
    for (int i = 0; i < 4; i++)
        #pragma unroll
        for (int j = 0; j < 4; j++) acc[i][j] = 0.f;

    for (int kt = 0; kt < Kd; kt += 16) {
        #pragma unroll
        for (int l = 0; l < 4; l++) {
            int e = tid + l * 256;
            int r = e >> 4, k = e & 15;
            Al[r][k] = A[(size_t)(by * 64 + r) * Kd + kt + k];
        }
        #pragma unroll
        for (int l = 0; l < 4; l++) {
            int e = tid + l * 256;
            int r = e >> 6, n = e & 63;
            Bl[r][n] = B[(size_t)(kt + r) * Nd + bx * 64 + n];
        }
        __syncthreads();
        #pragma unroll
        for (int k = 0; k < 16; k++) {
            float a[4], b[4];
            #pragma unroll
            for (int i = 0; i < 4; i++) a[i] = Al[ty * 4 + i][k];
            #pragma unroll
            for (int j = 0; j < 4; j++) b[j] = Bl[k][tx * 4 + j];
            #pragma unroll
            for (int i = 0; i < 4; i++)
                #pragma unroll
                for (int j = 0; j < 4; j++) acc[i][j] = fmaf(a[i], b[j], acc[i][j]);
        }
        __syncthreads();
    }
    #pragma unroll
    for (int i = 0; i < 4; i++)
        #pragma unroll
        for (int j = 0; j < 4; j++)
            C[(size_t)(by * 64 + ty * 4 + i) * Nd + bx * 64 + tx * 4 + j] = acc[i][j];
}

// ---------------- column sums of P: colsum[f] = sum_j P[j,f] ----------------
__global__ __launch_bounds__(256) void k_colsum(const float* __restrict__ P, float* __restrict__ colsum, int Fd) {
    int f = blockIdx.x * 256 + threadIdx.x;
    int r0 = blockIdx.y * (NPTS / 64);
    float s = 0.f;
    for (int r = 0; r < NPTS / 64; r++) s += P[(size_t)(r0 + r) * Fd + f];
    atomicAdd(&colsum[f], s);
}

// ---------------- aggregation + skip + bias + activation (dual-mode) ----------------
template <int ACT>
__global__ __launch_bounds__(256) void k_aggregate(const float* __restrict__ P, float* __restrict__ OUT,
        const float* __restrict__ skip, const float* __restrict__ bias,
        const float* __restrict__ inv, const unsigned int* __restrict__ mask,
        const float* __restrict__ colsum, int Fd) {
    __shared__ unsigned short list[LISTCAP];
    __shared__ int cnt_total;
    __shared__ int pos;
    int i = blockIdx.x, tid = threadIdx.x;
    if (tid == 0) { cnt_total = 0; pos = 0; }
    __syncthreads();
    unsigned int w = mask[(size_t)i * (NPTS / 32) + tid];  // 256 words, 256 threads
    atomicAdd(&cnt_total, __popc(w));
    __syncthreads();
    const int deg = cnt_total;
    const bool comp = deg > 4096;
    unsigned int wm = comp ? ~w : w;
    if (comp && tid == (i >> 5)) wm &= ~(1u << (i & 31));   // exclude self from complement
    while (wm) {
        int b = __ffs(wm) - 1;
        wm &= wm - 1;
        int pp = atomicAdd(&pos, 1);
        list[pp] = (unsigned short)(tid * 32 + b);
    }
    __syncthreads();
    const int n = comp ? (NPTS - 1 - deg) : deg;
    const float vinv = inv[i];
    for (int f = tid; f < Fd; f += 256) {
        float s = 0.f;
        for (int q = 0; q < n; q++) s += P[(size_t)list[q] * Fd + f];
        const float pif = P[(size_t)i * Fd + f];
        const float nb = comp ? (colsum[f] - pif - s) : s;
        float o = pif * skip[f] + vinv * nb + bias[f];
        if (ACT == 1) o = (o > 0.f) ? 1.0507009873554805f * o : 0.f;
        OUT[(size_t)i * Fd + f] = o;
    }
}

// ---------------- logits + softmax -> assign ----------------
__global__ void k_assign(const float* __restrict__ emb, const float* __restrict__ Wt,
                         const float* __restrict__ bt, float* __restrict__ assign) {
    int i = blockIdx.x, lane = threadIdx.x;  // 64 threads
    float e[4];
    #pragma unroll
    for (int m = 0; m < 4; m++) e[m] = emb[(size_t)i * FOUT + lane + 64 * m];
    float logit[NCLU];
    #pragma unroll
    for (int c = 0; c < NCLU; c++) {
        float p = 0.f;
        #pragma unroll
        for (int m = 0; m < 4; m++) p = fmaf(e[m], Wt[c * FOUT + lane + 64 * m], p);
        #pragma unroll
        for (int off = 32; off > 0; off >>= 1) p += __shfl_xor(p, off);
        logit[c] = p + bt[c];
    }
    float mx = logit[0];
    #pragma unroll
    for (int c = 1; c < NCLU; c++) mx = fmaxf(mx, logit[c]);
    float sum = 0.f, pr[NCLU];
    #pragma unroll
    for (int c = 0; c < NCLU; c++) { pr[c] = expf(logit[c] - mx); sum += pr[c]; }
    float isum = 1.f / sum;
    if (lane < NCLU) {
        float v = 0.f;
        #pragma unroll
        for (int c = 0; c < NCLU; c++) if (lane == c) v = pr[c];
        assign[(size_t)i * NCLU + lane] = v * isum;
    }
}

// ---------------- stats: colA[c], v[c] = sum_i assign[i,c]*deg[i], Esum = sum deg ----------------
__global__ __launch_bounds__(256) void k_stats(const float* __restrict__ assign,
        const float* __restrict__ degf, float* __restrict__ colA,
        float* __restrict__ vvec, float* __restrict__ Esum) {
    __shared__ float sc[NCLU], sv[NCLU], se;
    int tid = threadIdx.x;
    if (tid < NCLU) { sc[tid] = 0.f; sv[tid] = 0.f; }
    if (tid == 0) se = 0.f;
    __syncthreads();
    int i = blockIdx.x * 256 + tid;
    const float d = degf[i];
    const float* ar = assign + (size_t)i * NCLU;
    float ed = d;
    #pragma unroll
    for (int off = 32; off > 0; off >>= 1) ed += __shfl_xor(ed, off);
    if ((tid & 63) == 0) atomicAdd(&se, ed);
    #pragma unroll
    for (int c = 0; c < NCLU; c++) {
        float a = ar[c];
        float av = a * d;
        #pragma unroll
        for (int off = 32; off > 0; off >>= 1) { a += __shfl_xor(a, off); av += __shfl_xor(av, off); }
        if ((tid & 63) == 0) { atomicAdd(&sc[c], a); atomicAdd(&sv[c], av); }
    }
    __syncthreads();
    if (tid < NCLU) { atomicAdd(&colA[tid], sc[tid]); atomicAdd(&vvec[tid], sv[tid]); }
    if (tid == NCLU) atomicAdd(Esum, se);
}

// ---------------- spectral: Tpart[i] (no atomics) ----------------
__global__ __launch_bounds__(256) void k_spectral(const unsigned int* __restrict__ mask,
        const float* __restrict__ assign, const float* __restrict__ colA,
        float* __restrict__ Tpart) {
    __shared__ unsigned short list[LISTCAP];
    __shared__ int cnt_total;
    __shared__ int pos;
    __shared__ float red[4][NCLU];
    int i = blockIdx.x, tid = threadIdx.x;
    if (tid == 0) { cnt_total = 0; pos = 0; }
    __syncthreads();
    unsigned int w = mask[(size_t)i * (NPTS / 32) + tid];
    atomicAdd(&cnt_total, __popc(w));
    __syncthreads();
    const int deg = cnt_total;
    const bool comp = deg > 4096;
    unsigned int wm = comp ? ~w : w;
    if (comp && tid == (i >> 5)) wm &= ~(1u << (i & 31));
    while (wm) {
        int b = __ffs(wm) - 1;
        wm &= wm - 1;
        int pp = atomicAdd(&pos, 1);
        list[pp] = (unsigned short)(tid * 32 + b);
    }
    __syncthreads();
    const int n = comp ? (NPTS - 1 - deg) : deg;
    float yc[NCLU];
    #pragma unroll
    for (int c = 0; c < NCLU; c++) yc[c] = 0.f;
    for (int q = tid; q < n; q += 256) {
        const float* aj = assign + (size_t)list[q] * NCLU;
        #pragma unroll
        for (int c = 0; c < NCLU; c++) yc[c] += aj[c];
    }
    #pragma unroll
    for (int c = 0; c < NCLU; c++) {
        #pragma unroll
        for (int off = 32; off > 0; off >>= 1) yc[c] += __shfl_xor(yc[c], off);
    }
    int wv = tid >> 6, lane = tid & 63;
    if (lane == 0) {
        #pragma unroll
        for (int c = 0; c < NCLU; c++) red[wv][c] = yc[c];
    }
    __syncthreads();
    if (tid == 0) {
        const float* ai = assign + (size_t)i * NCLU;
        float t = 0.f;
        #pragma unroll
        for (int c = 0; c < NCLU; c++) {
            float y = red[0][c] + red[1][c] + red[2][c] + red[3][c];
            if (comp) y = colA[c] - ai[c] - y;
            t = fmaf(y, ai[c], t);
        }
        Tpart[i] = t;
    }
}

// ---------------- final scalar: reduce Tpart + combine ----------------
__global__ __launch_bounds__(256) void k_final(const float* __restrict__ Tpart,
        const float* __restrict__ v, const float* __restrict__ Esum, float* __restrict__ out) {
    __shared__ float red[256];
    int tid = threadIdx.x;
    float s = 0.f;
    for (int i = tid; i < NPTS; i += 256) s += Tpart[i];
    red[tid] = s; __syncthreads();
    for (int off = 128; off > 0; off >>= 1) {
        if (tid < off) red[tid] += red[tid + off];
        __syncthreads();
    }
    if (tid == 0) {
        float E = *Esum;
        float v2 = 0.f;
        for (int c = 0; c < NCLU; c++) v2 += v[c] * v[c];
        float tr_norm = v2 / (2.f * E);
        out[0] = -(red[0] - tr_norm) / (2.f * E);
    }
}

extern "C" void kernel_launch(void* const* d_in, const int* in_sizes, int n_in,
                              void* d_out, int out_size, void* d_ws, size_t ws_size,
                              hipStream_t stream) {
    const float* x     = (const float*)d_in[0];
    const float* W1    = (const float*)d_in[1];
    const float* b1    = (const float*)d_in[2];
    const float* skip1 = (const float*)d_in[3];
    const float* W2    = (const float*)d_in[4];
    const float* b2    = (const float*)d_in[5];
    const float* skip2 = (const float*)d_in[6];
    const float* Wt    = (const float*)d_in[7];
    const float* bt    = (const float*)d_in[8];

    char* ws = (char*)d_ws;
    float* bufA = (float*)ws;                                   // 16 MB  [N x 512]
    float* bufB = (float*)(ws + ((size_t)16 << 20));            // 16 MB  [N x 512]
    unsigned int* mask = (unsigned int*)(ws + ((size_t)32 << 20)); // 8 MB bitmask
    char* p = ws + ((size_t)40 << 20);
    float* sq     = (float*)p; p += NPTS * 4;
    float* degf   = (float*)p; p += NPTS * 4;
    float* inv    = (float*)p; p += NPTS * 4;
    int*   topidx = (int*)p;   p += (size_t)NPTS * KNEI * 4;
    float* assign = (float*)p; p += (size_t)NPTS * NCLU * 4;
    float* Tpart  = (float*)p; p += NPTS * 4;
    float* tpv    = (float*)p; p += (size_t)NPTS * GR_CHUNKS * KNEI * 4;  // 1.31 MB
    int*   tpi    = (int*)p;   p += (size_t)NPTS * GR_CHUNKS * KNEI * 4;  // 1.31 MB
    // contiguous zero-region: Esum, vvec[10], colA[10], colsum1[512], colsum2[256]
    float* Esum    = (float*)p; p += 4;
    float* vvec    = (float*)p; p += NCLU * 4;
    float* colA    = (float*)p; p += NCLU * 4;
    float* colsum1 = (float*)p; p += FHID * 4;
    float* colsum2 = (float*)p; p += FOUT * 4;

    // xb (bf16 copy of x, 8MB) aliases bufA: dead before k_gemm writes bufA.
    unsigned short* xb = (unsigned short*)bufA;

    hipMemsetAsync(mask, 0, (size_t)NPTS * (NPTS / 32) * 4, stream); // 8 MB
    hipMemsetAsync(Esum, 0, (1 + 2 * NCLU + FHID + FOUT) * sizeof(float), stream);

    k_sumsq<<<NPTS, 256, 0, stream>>>(x, sq);
    k_tobf16<<<(NPTS * FIN / 4) / 256, 256, 0, stream>>>(x, xb);
    k_gram_topk<<<(NPTS / GR_ROWS) * GR_CHUNKS, 256, 0, stream>>>(xb, sq, tpv, tpi);
    k_topk_merge<<<NPTS / 256, 256, 0, stream>>>(tpv, tpi, topidx);
    k_set_edges<<<(NPTS * KNEI + 255) / 256, 256, 0, stream>>>(topidx, mask);
    k_degree<<<NPTS, 64, 0, stream>>>(mask, degf, inv);

    // layer 1: P = x @ W1 ; h = act1(P*skip1 + A_hat@P + b1)
    k_gemm<<<dim3(FHID / 64, NPTS / 64), 256, 0, stream>>>(x, W1, bufA, NPTS, FIN, FHID);
    k_colsum<<<dim3(FHID / 256, 64), 256, 0, stream>>>(bufA, colsum1, FHID);
    k_aggregate<1><<<NPTS, 256, 0, stream>>>(bufA, bufB, skip1, b1, inv, mask, colsum1, FHID);
    // layer 2: P2 = h @ W2 ; emb = P2*skip2 + A_hat@P2 + b2
    k_gemm<<<dim3(FOUT / 64, NPTS / 64), 256, 0, stream>>>(bufB, W2, bufA, NPTS, FHID, FOUT);
    k_colsum<<<dim3(FOUT / 256, 64), 256, 0, stream>>>(bufA, colsum2, FOUT);
    k_aggregate<0><<<NPTS, 256, 0, stream>>>(bufA, bufB, skip2, b2, inv, mask, colsum2, FOUT);

    k_assign<<<NPTS, 64, 0, stream>>>(bufB, Wt, bt, assign);
    k_stats<<<NPTS / 256, 256, 0, stream>>>(assign, degf, colA, vvec, Esum);
    k_spectral<<<NPTS, 256, 0, stream>>>(mask, assign, colA, Tpart);
    k_final<<<1, 256, 0, stream>>>(Tpart, vvec, Esum, (float*)d_out);
}

// Round 10
// 948.781 us; speedup vs baseline: 1.4540x; 1.4540x over previous
//
#include <hip/hip_runtime.h>
#include <math.h>
#include <stdint.h>

#define NPTS 8192
#define FIN 512
#define FHID 512
#define FOUT 256
#define NCLU 10
#define KNEI 10
#define GAMMA_F 2.0f
#define LISTCAP 4160   // > 4096 direct cap and > 4095 complement cap

typedef __attribute__((ext_vector_type(4))) float f32x4;
typedef __attribute__((ext_vector_type(8))) short bf16x8;

// ---------------- sum of squares per row ----------------
__global__ void k_sumsq(const float* __restrict__ x, float* __restrict__ sq) {
    int row = blockIdx.x;
    const float* xr = x + (size_t)row * FIN;
    float s = 0.f;
    for (int k = threadIdx.x; k < FIN; k += 256) s += xr[k] * xr[k];
    __shared__ float red[256];
    red[threadIdx.x] = s; __syncthreads();
    for (int off = 128; off > 0; off >>= 1) {
        if (threadIdx.x < off) red[threadIdx.x] += red[threadIdx.x + off];
        __syncthreads();
    }
    if (threadIdx.x == 0) sq[row] = red[0];
}

// ---------------- f32 -> bf16 (RNE) ----------------
__global__ void k_tobf16(const float* __restrict__ x, unsigned short* __restrict__ xb) {
    int i = blockIdx.x * 256 + threadIdx.x;   // one float4 per thread
    f32x4 v = reinterpret_cast<const f32x4*>(x)[i];
    ushort4 o;
    #pragma unroll
    for (int e = 0; e < 4; e++) {
        union { float f; unsigned u; } cvt; cvt.f = v[e];
        unsigned r = (cvt.u + 0x7FFFu + ((cvt.u >> 16) & 1u)) >> 16;
        ((unsigned short*)&o)[e] = (unsigned short)r;
    }
    reinterpret_cast<ushort4*>(xb)[i] = o;
}

// ---------------- fused MFMA gram + exp + per-row partial top-10 ----------------
// grid: 512 = 128 row-groups x 4 col-chunks. Block owns 64 rows (16/wave, A in
// registers); B staged in LDS (128 cols x 64 k, XOR-swizzled) shared by all 4
// waves -> B-traffic = (8192/64) x 8MB = 1 GB total (4x less than GR_ROWS=16).
#define GR_ROWS 64
#define GR_TW 128
#define GR_CHUNKS 4
#define GR_CHUNK_COLS (NPTS / GR_CHUNKS)            // 2048
#define GR_TILES_PER_CHUNK (GR_CHUNK_COLS / GR_TW)  // 16

__global__ __launch_bounds__(256, 2) void k_gram_topk(
    const unsigned short* __restrict__ xb, const float* __restrict__ sq,
    float* __restrict__ tpv, int* __restrict__ tpi)
{
    __shared__ short Bl[128][64];                 // 16 KB, row = col, 64 k, swizzled
    __shared__ float Sl[GR_ROWS][GR_TW + 1];      // 33 KB
    __shared__ float tval[GR_ROWS][KNEI];
    __shared__ int   tidxs[GR_ROWS][KNEI];

    const int tid  = threadIdx.x;
    const int lane = tid & 63;
    const int wv   = tid >> 6;            // 0..3
    const int rg   = blockIdx.x >> 2;
    const int ch   = blockIdx.x & 3;
    const int r0   = rg * GR_ROWS;

    for (int e = tid; e < GR_ROWS * KNEI; e += 256) {
        tval[e / KNEI][e % KNEI] = -INFINITY;
        tidxs[e / KNEI][e % KNEI] = 0x7fffffff;
    }

    // A fragments: wave wv owns rows r0+wv*16 .. +16, full K in registers
    const int arow  = r0 + wv * 16 + (lane & 15);
    const int akoff = (lane >> 4) * 8;
    bf16x8 afr[16];
    #pragma unroll
    for (int ks = 0; ks < 16; ks++)
        afr[ks] = *reinterpret_cast<const bf16x8*>(xb + (size_t)arow * FIN + ks * 32 + akoff);

    float si_r[4];
    #pragma unroll
    for (int r = 0; r < 4; r++) si_r[r] = sq[r0 + wv * 16 + (lane >> 4) * 4 + r];

    const int stg_row = tid >> 1, stg_seg = tid & 1;
    __syncthreads();

    for (int t = 0; t < GR_TILES_PER_CHUNK; ++t) {
        const int c0 = ch * GR_CHUNK_COLS + t * GR_TW;
        f32x4 acc[8];
        #pragma unroll
        for (int ct = 0; ct < 8; ct++) acc[ct] = (f32x4){0.f, 0.f, 0.f, 0.f};

        for (int kc = 0; kc < 8; ++kc) {
            // stage B[128 cols][64 k] for k in [kc*64, kc*64+64), XOR-swizzled
            {
                const unsigned short* src = xb + (size_t)(c0 + stg_row) * FIN + kc * 64 + stg_seg * 32;
                #pragma unroll
                for (int q = 0; q < 4; q++) {
                    int kk8 = stg_seg * 4 + q;
                    *reinterpret_cast<bf16x8*>(&Bl[stg_row][(kk8 ^ (stg_row & 7)) * 8]) =
                        *reinterpret_cast<const bf16x8*>(src + q * 8);
                }
            }
            __syncthreads();
            #pragma unroll
            for (int ksl = 0; ksl < 2; ++ksl) {
                #pragma unroll
                for (int ct = 0; ct < 8; ct++) {
                    const int cl = ct * 16 + (lane & 15);
                    const int q = ksl * 4 + (lane >> 4);
                    bf16x8 bfr = *reinterpret_cast<const bf16x8*>(&Bl[cl][(q ^ (cl & 7)) * 8]);
                    acc[ct] = __builtin_amdgcn_mfma_f32_16x16x32_bf16(afr[kc * 2 + ksl], bfr, acc[ct], 0, 0, 0);
                }
            }
            __syncthreads();
        }

        // epilogue: S = exp(-d2/2), diag = -inf
        #pragma unroll
        for (int ct = 0; ct < 8; ct++) {
            const int col = ct * 16 + (lane & 15);
            const int gj  = c0 + col;
            const float sjv = sq[gj];
            #pragma unroll
            for (int r = 0; r < 4; r++) {
                const int row = wv * 16 + (lane >> 4) * 4 + r;
                const int gi  = r0 + row;
                const float d2 = si_r[r] + sjv - 2.f * acc[ct][r];
                Sl[row][col] = (gj == gi) ? -INFINITY : expf(-d2 * 0.5f);
            }
        }
        __syncthreads();

        // top-10 update, strict order (val desc, idx asc). wave wv owns rows wv*16..+16.
        for (int q2 = 0; q2 < 16; ++q2) {
            int r = wv * 16 + q2;
            for (int base = 0; base < GR_TW; base += 64) {
                float v = Sl[r][base + lane];
                int gj = c0 + base + lane;
                float rv9 = tval[r][KNEI - 1];
                int ri9 = tidxs[r][KNEI - 1];
                unsigned long long bal = __ballot(v > rv9 || (v == rv9 && gj < ri9));
                if (lane == 0 && bal) {
                    while (bal) {
                        int l = __ffsll((unsigned long long)bal) - 1;
                        bal &= bal - 1;
                        float cv = Sl[r][base + l];
                        int cj = c0 + base + l;
                        float a9 = tval[r][KNEI - 1];
                        int i9 = tidxs[r][KNEI - 1];
                        if (cv > a9 || (cv == a9 && cj < i9)) {
                            int pp = KNEI - 1;
                            tval[r][pp] = cv; tidxs[r][pp] = cj;
                            while (pp > 0) {
                                float pv = tval[r][pp - 1]; int pi = tidxs[r][pp - 1];
                                if (cv > pv || (cv == pv && cj < pi)) {
                                    tval[r][pp] = pv; tidxs[r][pp] = pi;
                                    tval[r][pp - 1] = cv; tidxs[r][pp - 1] = cj;
                                    --pp;
                                } else break;
                            }
                        }
                    }
                }
            }
        }
        __syncthreads();
    }

    for (int e = tid; e < GR_ROWS * KNEI; e += 256) {
        int r = e / KNEI, m = e % KNEI;
        size_t o = (((size_t)(r0 + r) * GR_CHUNKS) + ch) * KNEI + m;
        tpv[o] = tval[r][m];
        tpi[o] = tidxs[r][m];
    }
}

// ---------------- merge 4 partial top-10 lists per row ----------------
__global__ __launch_bounds__(256) void k_topk_merge(const float* __restrict__ tpv,
        const int* __restrict__ tpi, int* __restrict__ topidx) {
    int r = blockIdx.x * 256 + threadIdx.x;
    int p[GR_CHUNKS] = {0, 0, 0, 0};
    #pragma unroll
    for (int m = 0; m < KNEI; m++) {
        float bv = -INFINITY; int bi = 0x7fffffff; int bc = 0;
        #pragma unroll
        for (int c = 0; c < GR_CHUNKS; c++) {
            if (p[c] < KNEI) {
                size_t o = (((size_t)r * GR_CHUNKS) + c) * KNEI + p[c];
                float v = tpv[o];
                int idx = tpi[o];
                if (v > bv || (v == bv && idx < bi)) { bv = v; bi = idx; bc = c; }
            }
        }
        topidx[(size_t)r * KNEI + m] = bi;
        p[bc]++;
    }
}

// ---------------- build symmetric adjacency bitmask ----------------
__global__ void k_set_edges(const int* __restrict__ topidx, unsigned int* __restrict__ mask) {
    int t = blockIdx.x * 256 + threadIdx.x;
    if (t >= NPTS * KNEI) return;
    int i = t / KNEI;
    int j = topidx[t];
    atomicOr(&mask[(size_t)i * (NPTS / 32) + (j >> 5)], 1u << (j & 31));
    atomicOr(&mask[(size_t)j * (NPTS / 32) + (i >> 5)], 1u << (i & 31));
}

// ---------------- degree, inv ----------------
__global__ void k_degree(const unsigned int* __restrict__ mask, float* __restrict__ degf,
                         float* __restrict__ inv) {
    int i = blockIdx.x, lane = threadIdx.x;  // 64 threads
    int c = 0;
    for (int w = lane; w < NPTS / 32; w += 64) c += __popc(mask[(size_t)i * (NPTS / 32) + w]);
    for (int off = 32; off > 0; off >>= 1) c += __shfl_xor(c, off);
    if (lane == 0) {
        float d = (float)c;
        degf[i] = d;
        inv[i] = (c > 0) ? 1.0f / d : 0.0f;
    }
}

// ---------------- generic f32 GEMM ----------------
__global__ __launch_bounds__(256) void k_gemm(const float* __restrict__ A, const float* __restrict__ B,
                                              float* __restrict__ C, int M, int Kd, int Nd) {
    __shared__ float Al[64][17];
    __shared__ float Bl[16][65];
    int tid = threadIdx.x;
    int bx = blockIdx.x, by = blockIdx.y;
    int tx = tid & 15, ty = tid >> 4;
    float acc[4][4];
    #pragma unroll
    for (int i = 0; i < 4; i++)
        #pragma unroll
        for (int j = 0; j < 4; j++) acc[i][j] = 0.f;

    for (int kt = 0; kt < Kd; kt += 16) {
        #pragma unroll
        for (int l = 0; l < 4; l++) {
            int e = tid + l * 256;
            int r = e >> 4, k = e & 15;
            Al[r][k] = A[(size_t)(by * 64 + r) * Kd + kt + k];
        }
        #pragma unroll
        for (int l = 0; l < 4; l++) {
            int e = tid + l * 256;
            int r = e >> 6, n = e & 63;
            Bl[r][n] = B[(size_t)(kt + r) * Nd + bx * 64 + n];
        }
        __syncthreads();
        #pragma unroll
        for (int k = 0; k < 16; k++) {
            float a[4], b[4];
            #pragma unroll
            for (int i = 0; i < 4; i++) a[i] = Al[ty * 4 + i][k];
            #pragma unroll
            for (int j = 0; j < 4; j++) b[j] = Bl[k][tx * 4 + j];
            #pragma unroll
            for (int i = 0; i < 4; i++)
                #pragma unroll
                for (int j = 0; j < 4; j++) acc[i][j] = fmaf(a[i], b[j], acc[i][j]);
        }
        __syncthreads();
    }
    #pragma unroll
    for (int i = 0; i < 4; i++)
        #pragma unroll
        for (int j = 0; j < 4; j++)
            C[(size_t)(by * 64 + ty * 4 + i) * Nd + bx * 64 + tx * 4 + j] = acc[i][j];
}

// ---------------- column sums of P: colsum[f] = sum_j P[j,f] ----------------
__global__ __launch_bounds__(256) void k_colsum(const float* __restrict__ P, float* __restrict__ colsum, int Fd) {
    int f = blockIdx.x * 256 + threadIdx.x;
    int r0 = blockIdx.y * (NPTS / 64);
    float s = 0.f;
    for (int r = 0; r < NPTS / 64; r++) s += P[(size_t)(r0 + r) * Fd + f];
    atomicAdd(&colsum[f], s);
}

// ---------------- aggregation + skip + bias + activation (dual-mode) ----------------
template <int ACT>
__global__ __launch_bounds__(256) void k_aggregate(const float* __restrict__ P, float* __restrict__ OUT,
        const float* __restrict__ skip, const float* __restrict__ bias,
        const float* __restrict__ inv, const unsigned int* __restrict__ mask,
        const float* __restrict__ colsum, int Fd) {
    __shared__ unsigned short list[LISTCAP];
    __shared__ int cnt_total;
    __shared__ int pos;
    int i = blockIdx.x, tid = threadIdx.x;
    if (tid == 0) { cnt_total = 0; pos = 0; }
    __syncthreads();
    unsigned int w = mask[(size_t)i * (NPTS / 32) + tid];  // 256 words, 256 threads
    atomicAdd(&cnt_total, __popc(w));
    __syncthreads();
    const int deg = cnt_total;
    const bool comp = deg > 4096;
    unsigned int wm = comp ? ~w : w;
    if (comp && tid == (i >> 5)) wm &= ~(1u << (i & 31));   // exclude self from complement
    while (wm) {
        int b = __ffs(wm) - 1;
        wm &= wm - 1;
        int pp = atomicAdd(&pos, 1);
        list[pp] = (unsigned short)(tid * 32 + b);
    }
    __syncthreads();
    const int n = comp ? (NPTS - 1 - deg) : deg;
    const float vinv = inv[i];
    for (int f = tid; f < Fd; f += 256) {
        float s = 0.f;
        for (int q = 0; q < n; q++) s += P[(size_t)list[q] * Fd + f];
        const float pif = P[(size_t)i * Fd + f];
        const float nb = comp ? (colsum[f] - pif - s) : s;
        float o = pif * skip[f] + vinv * nb + bias[f];
        if (ACT == 1) o = (o > 0.f) ? 1.0507009873554805f * o : 0.f;
        OUT[(size_t)i * Fd + f] = o;
    }
}

// ---------------- logits + softmax -> assign ----------------
__global__ void k_assign(const float* __restrict__ emb, const float* __restrict__ Wt,
                         const float* __restrict__ bt, float* __restrict__ assign) {
    int i = blockIdx.x, lane = threadIdx.x;  // 64 threads
    float e[4];
    #pragma unroll
    for (int m = 0; m < 4; m++) e[m] = emb[(size_t)i * FOUT + lane + 64 * m];
    float logit[NCLU];
    #pragma unroll
    for (int c = 0; c < NCLU; c++) {
        float p = 0.f;
        #pragma unroll
        for (int m = 0; m < 4; m++) p = fmaf(e[m], Wt[c * FOUT + lane + 64 * m], p);
        #pragma unroll
        for (int off = 32; off > 0; off >>= 1) p += __shfl_xor(p, off);
        logit[c] = p + bt[c];
    }
    float mx = logit[0];
    #pragma unroll
    for (int c = 1; c < NCLU; c++) mx = fmaxf(mx, logit[c]);
    float sum = 0.f, pr[NCLU];
    #pragma unroll
    for (int c = 0; c < NCLU; c++) { pr[c] = expf(logit[c] - mx); sum += pr[c]; }
    float isum = 1.f / sum;
    if (lane < NCLU) {
        float v = 0.f;
        #pragma unroll
        for (int c = 0; c < NCLU; c++) if (lane == c) v = pr[c];
        assign[(size_t)i * NCLU + lane] = v * isum;
    }
}

// ---------------- stats: colA[c], v[c] = sum_i assign[i,c]*deg[i], Esum = sum deg ----------------
__global__ __launch_bounds__(256) void k_stats(const float* __restrict__ assign,
        const float* __restrict__ degf, float* __restrict__ colA,
        float* __restrict__ vvec, float* __restrict__ Esum) {
    __shared__ float sc[NCLU], sv[NCLU], se;
    int tid = threadIdx.x;
    if (tid < NCLU) { sc[tid] = 0.f; sv[tid] = 0.f; }
    if (tid == 0) se = 0.f;
    __syncthreads();
    int i = blockIdx.x * 256 + tid;
    const float d = degf[i];
    const float* ar = assign + (size_t)i * NCLU;
    float ed = d;
    #pragma unroll
    for (int off = 32; off > 0; off >>= 1) ed += __shfl_xor(ed, off);
    if ((tid & 63) == 0) atomicAdd(&se, ed);
    #pragma unroll
    for (int c = 0; c < NCLU; c++) {
        float a = ar[c];
        float av = a * d;
        #pragma unroll
        for (int off = 32; off > 0; off >>= 1) { a += __shfl_xor(a, off); av += __shfl_xor(av, off); }
        if ((tid & 63) == 0) { atomicAdd(&sc[c], a); atomicAdd(&sv[c], av); }
    }
    __syncthreads();
    if (tid < NCLU) { atomicAdd(&colA[tid], sc[tid]); atomicAdd(&vvec[tid], sv[tid]); }
    if (tid == NCLU) atomicAdd(Esum, se);
}

// ---------------- spectral: Tpart[i] (no atomics) ----------------
__global__ __launch_bounds__(256) void k_spectral(const unsigned int* __restrict__ mask,
        const float* __restrict__ assign, const float* __restrict__ colA,
        float* __restrict__ Tpart) {
    __shared__ unsigned short list[LISTCAP];
    __shared__ int cnt_total;
    __shared__ int pos;
    __shared__ float red[4][NCLU];
    int i = blockIdx.x, tid = threadIdx.x;
    if (tid == 0) { cnt_total = 0; pos = 0; }
    __syncthreads();
    unsigned int w = mask[(size_t)i * (NPTS / 32) + tid];
    atomicAdd(&cnt_total, __popc(w));
    __syncthreads();
    const int deg = cnt_total;
    const bool comp = deg > 4096;
    unsigned int wm = comp ? ~w : w;
    if (comp && tid == (i >> 5)) wm &= ~(1u << (i & 31));
    while (wm) {
        int b = __ffs(wm) - 1;
        wm &= wm - 1;
        int pp = atomicAdd(&pos, 1);
        list[pp] = (unsigned short)(tid * 32 + b);
    }
    __syncthreads();
    const int n = comp ? (NPTS - 1 - deg) : deg;
    float yc[NCLU];
    #pragma unroll
    for (int c = 0; c < NCLU; c++) yc[c] = 0.f;
    for (int q = tid; q < n; q += 256) {
        const float* aj = assign + (size_t)list[q] * NCLU;
        #pragma unroll
        for (int c = 0; c < NCLU; c++) yc[c] += aj[c];
    }
    #pragma unroll
    for (int c = 0; c < NCLU; c++) {
        #pragma unroll
        for (int off = 32; off > 0; off >>= 1) yc[c] += __shfl_xor(yc[c], off);
    }
    int wv = tid >> 6, lane = tid & 63;
    if (lane == 0) {
        #pragma unroll
        for (int c = 0; c < NCLU; c++) red[wv][c] = yc[c];
    }
    __syncthreads();
    if (tid == 0) {
        const float* ai = assign + (size_t)i * NCLU;
        float t = 0.f;
        #pragma unroll
        for (int c = 0; c < NCLU; c++) {
            float y = red[0][c] + red[1][c] + red[2][c] + red[3][c];
            if (comp) y = colA[c] - ai[c] - y;
            t = fmaf(y, ai[c], t);
        }
        Tpart[i] = t;
    }
}

// ---------------- final scalar: reduce Tpart + combine ----------------
__global__ __launch_bounds__(256) void k_final(const float* __restrict__ Tpart,
        const float* __restrict__ v, const float* __restrict__ Esum, float* __restrict__ out) {
    __shared__ float red[256];
    int tid = threadIdx.x;
    float s = 0.f;
    for (int i = tid; i < NPTS; i += 256) s += Tpart[i];
    red[tid] = s; __syncthreads();
    for (int off = 128; off > 0; off >>= 1) {
        if (tid < off) red[tid] += red[tid + off];
        __syncthreads();
    }
    if (tid == 0) {
        float E = *Esum;
        float v2 = 0.f;
        for (int c = 0; c < NCLU; c++) v2 += v[c] * v[c];
        float tr_norm = v2 / (2.f * E);
        out[0] = -(red[0] - tr_norm) / (2.f * E);
    }
}

extern "C" void kernel_launch(void* const* d_in, const int* in_sizes, int n_in,
                              void* d_out, int out_size, void* d_ws, size_t ws_size,
                              hipStream_t stream) {
    const float* x     = (const float*)d_in[0];
    const float* W1    = (const float*)d_in[1];
    const float* b1    = (const float*)d_in[2];
    const float* skip1 = (const float*)d_in[3];
    const float* W2    = (const float*)d_in[4];
    const float* b2    = (const float*)d_in[5];
    const float* skip2 = (const float*)d_in[6];
    const float* Wt    = (const float*)d_in[7];
    const float* bt    = (const float*)d_in[8];

    char* ws = (char*)d_ws;
    float* bufA = (float*)ws;                                   // 16 MB  [N x 512]
    float* bufB = (float*)(ws + ((size_t)16 << 20));            // 16 MB  [N x 512]
    unsigned int* mask = (unsigned int*)(ws + ((size_t)32 << 20)); // 8 MB bitmask
    char* p = ws + ((size_t)40 << 20);
    float* sq     = (float*)p; p += NPTS * 4;
    float* degf   = (float*)p; p += NPTS * 4;
    float* inv    = (float*)p; p += NPTS * 4;
    int*   topidx = (int*)p;   p += (size_t)NPTS * KNEI * 4;
    float* assign = (float*)p; p += (size_t)NPTS * NCLU * 4;
    float* Tpart  = (float*)p; p += NPTS * 4;
    float* tpv    = (float*)p; p += (size_t)NPTS * GR_CHUNKS * KNEI * 4;  // 1.31 MB
    int*   tpi    = (int*)p;   p += (size_t)NPTS * GR_CHUNKS * KNEI * 4;  // 1.31 MB
    // contiguous zero-region: Esum, vvec[10], colA[10], colsum1[512], colsum2[256]
    float* Esum    = (float*)p; p += 4;
    float* vvec    = (float*)p; p += NCLU * 4;
    float* colA    = (float*)p; p += NCLU * 4;
    float* colsum1 = (float*)p; p += FHID * 4;
    float* colsum2 = (float*)p; p += FOUT * 4;

    // xb (bf16 copy of x, 8MB) aliases bufA: dead before k_gemm writes bufA.
    unsigned short* xb = (unsigned short*)bufA;

    hipMemsetAsync(mask, 0, (size_t)NPTS * (NPTS / 32) * 4, stream); // 8 MB
    hipMemsetAsync(Esum, 0, (1 + 2 * NCLU + FHID + FOUT) * sizeof(float), stream);

    k_sumsq<<<NPTS, 256, 0, stream>>>(x, sq);
    k_tobf16<<<(NPTS * FIN / 4) / 256, 256, 0, stream>>>(x, xb);
    k_gram_topk<<<(NPTS / GR_ROWS) * GR_CHUNKS, 256, 0, stream>>>(xb, sq, tpv, tpi);
    k_topk_merge<<<NPTS / 256, 256, 0, stream>>>(tpv, tpi, topidx);
    k_set_edges<<<(NPTS * KNEI + 255) / 256, 256, 0, stream>>>(topidx, mask);
    k_degree<<<NPTS, 64, 0, stream>>>(mask, degf, inv);

    // layer 1: P = x @ W1 ; h = act1(P*skip1 + A_hat@P + b1)
    k_gemm<<<dim3(FHID / 64, NPTS / 64), 256, 0, stream>>>(x, W1, bufA, NPTS, FIN, FHID);
    k_colsum<<<dim3(FHID / 256, 64), 256, 0, stream>>>(bufA, colsum1, FHID);
    k_aggregate<1><<<NPTS, 256, 0, stream>>>(bufA, bufB, skip1, b1, inv, mask, colsum1, FHID);
    // layer 2: P2 = h @ W2 ; emb = P2*skip2 + A_hat@P2 + b2
    k_gemm<<<dim3(FOUT / 64, NPTS / 64), 256, 0, stream>>>(bufB, W2, bufA, NPTS, FHID, FOUT);
    k_colsum<<<dim3(FOUT / 256, 64), 256, 0, stream>>>(bufA, colsum2, FOUT);
    k_aggregate<0><<<NPTS, 256, 0, stream>>>(bufA, bufB, skip2, b2, inv, mask, colsum2, FOUT);

    k_assign<<<NPTS, 64, 0, stream>>>(bufB, Wt, bt, assign);
    k_stats<<<NPTS / 256, 256, 0, stream>>>(assign, degf, colA, vvec, Esum);
    k_spectral<<<NPTS, 256, 0, stream>>>(mask, assign, colA, Tpart);
    k_final<<<1, 256, 0, stream>>>(Tpart, vvec, Esum, (float*)d_out);
}

// Round 11
// 728.825 us; speedup vs baseline: 1.8928x; 1.3018x over previous
//
#include <hip/hip_runtime.h>
#include <math.h>
#include <stdint.h>

#define NPTS 8192
#define FIN 512
#define FHID 512
#define FOUT 256
#define NCLU 10
#define KNEI 10
#define GAMMA_F 2.0f
#define LISTCAP 4160   // > 4096 direct cap and > 4095 complement cap

typedef __attribute__((ext_vector_type(4))) float f32x4;
typedef __attribute__((ext_vector_type(8))) short bf16x8;

// ---------------- sum of squares per row ----------------
__global__ void k_sumsq(const float* __restrict__ x, float* __restrict__ sq) {
    int row = blockIdx.x;
    const float* xr = x + (size_t)row * FIN;
    float s = 0.f;
    for (int k = threadIdx.x; k < FIN; k += 256) s += xr[k] * xr[k];
    __shared__ float red[256];
    red[threadIdx.x] = s; __syncthreads();
    for (int off = 128; off > 0; off >>= 1) {
        if (threadIdx.x < off) red[threadIdx.x] += red[threadIdx.x + off];
        __syncthreads();
    }
    if (threadIdx.x == 0) sq[row] = red[0];
}

// ---------------- f32 -> bf16 (RNE) ----------------
__global__ void k_tobf16(const float* __restrict__ x, unsigned short* __restrict__ xb) {
    int i = blockIdx.x * 256 + threadIdx.x;   // one float4 per thread
    f32x4 v = reinterpret_cast<const f32x4*>(x)[i];
    ushort4 o;
    #pragma unroll
    for (int e = 0; e < 4; e++) {
        union { float f; unsigned u; } cvt; cvt.f = v[e];
        unsigned r = (cvt.u + 0x7FFFu + ((cvt.u >> 16) & 1u)) >> 16;
        ((unsigned short*)&o)[e] = (unsigned short)r;
    }
    reinterpret_cast<ushort4*>(xb)[i] = o;
}

// ---------------- fused MFMA gram + exp + per-row partial top-10 ----------------
// grid: 1024 = 128 row-groups x 8 col-chunks. Block owns 64 rows (16/wave, A in
// registers); B (128 cols x 64 k) double-buffered in LDS via register prefetch:
// one barrier per k-step, load latency hidden under MFMA. Top-k scanned directly
// from MFMA accumulators (no S staging in LDS). ch = blockIdx&7 == XCD id under
// round-robin -> each XCD streams a 1MB L2-resident chunk of xb.
#define GR_ROWS 64
#define GR_TW 128
#define GR_CHUNKS 8
#define GR_CHUNK_COLS (NPTS / GR_CHUNKS)            // 1024
#define GR_TILES_PER_CHUNK (GR_CHUNK_COLS / GR_TW)  // 8
#define GR_STEPS (GR_TILES_PER_CHUNK * 8)           // 64 k-steps (8 kc per tile)

__global__ __launch_bounds__(256, 3) void k_gram_topk(
    const unsigned short* __restrict__ xb, const float* __restrict__ sq,
    float* __restrict__ tpv, int* __restrict__ tpi)
{
    __shared__ short Bl[2][128][64];              // 32 KB double-buffered B
    __shared__ float tval[GR_ROWS][KNEI];
    __shared__ int   tidxs[GR_ROWS][KNEI];

    const int tid  = threadIdx.x;
    const int lane = tid & 63;
    const int wv   = tid >> 6;            // 0..3
    const int rg   = blockIdx.x >> 3;
    const int ch   = blockIdx.x & 7;
    const int r0   = rg * GR_ROWS;
    const int cbase = ch * GR_CHUNK_COLS;

    for (int e = tid; e < GR_ROWS * KNEI; e += 256) {
        tval[e / KNEI][e % KNEI] = -INFINITY;
        tidxs[e / KNEI][e % KNEI] = 0x7fffffff;
    }

    // A fragments: wave wv owns rows r0+wv*16 .. +16, full K in registers
    const int arow  = r0 + wv * 16 + (lane & 15);
    const int akoff = (lane >> 4) * 8;
    bf16x8 afr[16];
    #pragma unroll
    for (int ks = 0; ks < 16; ks++)
        afr[ks] = *reinterpret_cast<const bf16x8*>(xb + (size_t)arow * FIN + ks * 32 + akoff);

    float si_r[4];
    #pragma unroll
    for (int r = 0; r < 4; r++) si_r[r] = sq[r0 + wv * 16 + (lane >> 4) * 4 + r];

    const int stg_row = tid >> 1, stg_seg = tid & 1;

    // prefetch step 0 into registers, write buf 0
    bf16x8 pre[4];
    {
        const unsigned short* src = xb + (size_t)(cbase + stg_row) * FIN + stg_seg * 32;
        #pragma unroll
        for (int q = 0; q < 4; q++) pre[q] = *reinterpret_cast<const bf16x8*>(src + q * 8);
        #pragma unroll
        for (int q = 0; q < 4; q++) {
            int kk8 = stg_seg * 4 + q;
            *reinterpret_cast<bf16x8*>(&Bl[0][stg_row][(kk8 ^ (stg_row & 7)) * 8]) = pre[q];
        }
    }
    __syncthreads();   // buf0 ready; also covers tval init

    f32x4 acc[8];
    for (int u = 0; u < GR_STEPS; ++u) {
        const int t  = u >> 3, kc = u & 7;
        const int c0 = cbase + t * GR_TW;
        const int cur = u & 1;

        if (kc == 0) {
            #pragma unroll
            for (int ct = 0; ct < 8; ct++) acc[ct] = (f32x4){0.f, 0.f, 0.f, 0.f};
        }

        // issue next step's global loads (latency hides under MFMA + scan)
        if (u < GR_STEPS - 1) {
            const int u2 = u + 1, t2 = u2 >> 3, kc2 = u2 & 7;
            const unsigned short* src = xb + (size_t)(cbase + t2 * GR_TW + stg_row) * FIN + kc2 * 64 + stg_seg * 32;
            #pragma unroll
            for (int q = 0; q < 4; q++) pre[q] = *reinterpret_cast<const bf16x8*>(src + q * 8);
        }

        // MFMA from Bl[cur]
        #pragma unroll
        for (int ksl = 0; ksl < 2; ++ksl) {
            #pragma unroll
            for (int ct = 0; ct < 8; ct++) {
                const int cl = ct * 16 + (lane & 15);
                const int q = ksl * 4 + (lane >> 4);
                bf16x8 bfr = *reinterpret_cast<const bf16x8*>(&Bl[cur][cl][(q ^ (cl & 7)) * 8]);
                acc[ct] = __builtin_amdgcn_mfma_f32_16x16x32_bf16(afr[kc * 2 + ksl], bfr, acc[ct], 0, 0, 0);
            }
        }

        // tile complete: scan top-10 directly from accumulators (wave-local)
        if (kc == 7) {
            #pragma unroll
            for (int ct = 0; ct < 8; ct++) {
                const int gj  = c0 + ct * 16 + (lane & 15);
                const float sjv = sq[gj];
                float sv[4];
                #pragma unroll
                for (int r = 0; r < 4; r++) {
                    const int gi = r0 + wv * 16 + (lane >> 4) * 4 + r;
                    const float d2 = si_r[r] + sjv - 2.f * acc[ct][r];
                    sv[r] = (gj == gi) ? -INFINITY : expf(-d2 * 0.5f);
                }
                #pragma unroll
                for (int r = 0; r < 4; r++) {
                    const int myrow = wv * 16 + (lane >> 4) * 4 + r;
                    float t9 = tval[myrow][KNEI - 1];
                    int   i9 = tidxs[myrow][KNEI - 1];
                    unsigned long long bal = __ballot(sv[r] > t9 || (sv[r] == t9 && gj < i9));
                    while (bal) {
                        int l = __ffsll(bal) - 1;
                        bal &= bal - 1;
                        float cv = __shfl(sv[r], l);
                        int   cj = c0 + ct * 16 + (l & 15);
                        int   rfull = wv * 16 + (l >> 4) * 4 + r;
                        if (lane == 0) {
                            float a9 = tval[rfull][KNEI - 1];
                            int   i9b = tidxs[rfull][KNEI - 1];
                            if (cv > a9 || (cv == a9 && cj < i9b)) {
                                int pp = KNEI - 1;
                                tval[rfull][pp] = cv; tidxs[rfull][pp] = cj;
                                while (pp > 0) {
                                    float pv = tval[rfull][pp - 1]; int pi = tidxs[rfull][pp - 1];
                                    if (cv > pv || (cv == pv && cj < pi)) {
                                        tval[rfull][pp] = pv; tidxs[rfull][pp] = pi;
                                        tval[rfull][pp - 1] = cv; tidxs[rfull][pp - 1] = cj;
                                        --pp;
                                    } else break;
                                }
                            }
                        }
                    }
                }
            }
        }

        // write prefetched step into the other buffer
        if (u < GR_STEPS - 1) {
            #pragma unroll
            for (int q = 0; q < 4; q++) {
                int kk8 = stg_seg * 4 + q;
                *reinterpret_cast<bf16x8*>(&Bl[cur ^ 1][stg_row][(kk8 ^ (stg_row & 7)) * 8]) = pre[q];
            }
        }
        __syncthreads();
    }

    for (int e = tid; e < GR_ROWS * KNEI; e += 256) {
        int r = e / KNEI, m = e % KNEI;
        size_t o = (((size_t)(r0 + r) * GR_CHUNKS) + ch) * KNEI + m;
        tpv[o] = tval[r][m];
        tpi[o] = tidxs[r][m];
    }
}

// ---------------- merge 8 partial top-10 lists per row ----------------
__global__ __launch_bounds__(256) void k_topk_merge(const float* __restrict__ tpv,
        const int* __restrict__ tpi, int* __restrict__ topidx) {
    int r = blockIdx.x * 256 + threadIdx.x;
    int p[GR_CHUNKS];
    #pragma unroll
    for (int c = 0; c < GR_CHUNKS; c++) p[c] = 0;
    #pragma unroll
    for (int m = 0; m < KNEI; m++) {
        float bv = -INFINITY; int bi = 0x7fffffff; int bc = 0;
        #pragma unroll
        for (int c = 0; c < GR_CHUNKS; c++) {
            if (p[c] < KNEI) {
                size_t o = (((size_t)r * GR_CHUNKS) + c) * KNEI + p[c];
                float v = tpv[o];
                int idx = tpi[o];
                if (v > bv || (v == bv && idx < bi)) { bv = v; bi = idx; bc = c; }
            }
        }
        topidx[(size_t)r * KNEI + m] = bi;
        p[bc]++;
    }
}

// ---------------- build symmetric adjacency bitmask ----------------
__global__ void k_set_edges(const int* __restrict__ topidx, unsigned int* __restrict__ mask) {
    int t = blockIdx.x * 256 + threadIdx.x;
    if (t >= NPTS * KNEI) return;
    int i = t / KNEI;
    int j = topidx[t];
    atomicOr(&mask[(size_t)i * (NPTS / 32) + (j >> 5)], 1u << (j & 31));
    atomicOr(&mask[(size_t)j * (NPTS / 32) + (i >> 5)], 1u << (i & 31));
}

// ---------------- degree, inv ----------------
__global__ void k_degree(const unsigned int* __restrict__ mask, float* __restrict__ degf,
                         float* __restrict__ inv) {
    int i = blockIdx.x, lane = threadIdx.x;  // 64 threads
    int c = 0;
    for (int w = lane; w < NPTS / 32; w += 64) c += __popc(mask[(size_t)i * (NPTS / 32) + w]);
    for (int off = 32; off > 0; off >>= 1) c += __shfl_xor(c, off);
    if (lane == 0) {
        float d = (float)c;
        degf[i] = d;
        inv[i] = (c > 0) ? 1.0f / d : 0.0f;
    }
}

// ---------------- generic f32 GEMM ----------------
__global__ __launch_bounds__(256) void k_gemm(const float* __restrict__ A, const float* __restrict__ B,
                                              float* __restrict__ C, int M, int Kd, int Nd) {
    __shared__ float Al[64][17];
    __shared__ float Bl[16][65];
    int tid = threadIdx.x;
    int bx = blockIdx.x, by = blockIdx.y;
    int tx = tid & 15, ty = tid >> 4;
    float acc[4][4];
    #pragma unroll
    for (int i = 0; i < 4; i++)
        #pragma unroll
        for (int j = 0; j < 4; j++) acc[i][j] = 0.f;

    for (int kt = 0; kt < Kd; kt += 16) {
        #pragma unroll
        for (int l = 0; l < 4; l++) {
            int e = tid + l * 256;
            int r = e >> 4, k = e & 15;
            Al[r][k] = A[(size_t)(by * 64 + r) * Kd + kt + k];
        }
        #pragma unroll
        for (int l = 0; l < 4; l++) {
            int e = tid + l * 256;
            int r = e >> 6, n = e & 63;
            Bl[r][n] = B[(size_t)(kt + r) * Nd + bx * 64 + n];
        }
        __syncthreads();
        #pragma unroll
        for (int k = 0; k < 16; k++) {
            float a[4], b[4];
            #pragma unroll
            for (int i = 0; i < 4; i++) a[i] = Al[ty * 4 + i][k];
            #pragma unroll
            for (int j = 0; j < 4; j++) b[j] = Bl[k][tx * 4 + j];
            #pragma unroll
            for (int i = 0; i < 4; i++)
                #pragma unroll
                for (int j = 0; j < 4; j++) acc[i][j] = fmaf(a[i], b[j], acc[i][j]);
        }
        __syncthreads();
    }
    #pragma unroll
    for (int i = 0; i < 4; i++)
        #pragma unroll
        for (int j = 0; j < 4; j++)
            C[(size_t)(by * 64 + ty * 4 + i) * Nd + bx * 64 + tx * 4 + j] = acc[i][j];
}

// ---------------- column sums of P: colsum[f] = sum_j P[j,f] ----------------
__global__ __launch_bounds__(256) void k_colsum(const float* __restrict__ P, float* __restrict__ colsum, int Fd) {
    int f = blockIdx.x * 256 + threadIdx.x;
    int r0 = blockIdx.y * (NPTS / 64);
    float s = 0.f;
    for (int r = 0; r < NPTS / 64; r++) s += P[(size_t)(r0 + r) * Fd + f];
    atomicAdd(&colsum[f], s);
}

// ---------------- aggregation + skip + bias + activation (dual-mode) ----------------
template <int ACT>
__global__ __launch_bounds__(256) void k_aggregate(const float* __restrict__ P, float* __restrict__ OUT,
        const float* __restrict__ skip, const float* __restrict__ bias,
        const float* __restrict__ inv, const unsigned int* __restrict__ mask,
        const float* __restrict__ colsum, int Fd) {
    __shared__ unsigned short list[LISTCAP];
    __shared__ int cnt_total;
    __shared__ int pos;
    int i = blockIdx.x, tid = threadIdx.x;
    if (tid == 0) { cnt_total = 0; pos = 0; }
    __syncthreads();
    unsigned int w = mask[(size_t)i * (NPTS / 32) + tid];  // 256 words, 256 threads
    atomicAdd(&cnt_total, __popc(w));
    __syncthreads();
    const int deg = cnt_total;
    const bool comp = deg > 4096;
    unsigned int wm = comp ? ~w : w;
    if (comp && tid == (i >> 5)) wm &= ~(1u << (i & 31));   // exclude self from complement
    while (wm) {
        int b = __ffs(wm) - 1;
        wm &= wm - 1;
        int pp = atomicAdd(&pos, 1);
        list[pp] = (unsigned short)(tid * 32 + b);
    }
    __syncthreads();
    const int n = comp ? (NPTS - 1 - deg) : deg;
    const float vinv = inv[i];
    for (int f = tid; f < Fd; f += 256) {
        float s = 0.f;
        for (int q = 0; q < n; q++) s += P[(size_t)list[q] * Fd + f];
        const float pif = P[(size_t)i * Fd + f];
        const float nb = comp ? (colsum[f] - pif - s) : s;
        float o = pif * skip[f] + vinv * nb + bias[f];
        if (ACT == 1) o = (o > 0.f) ? 1.0507009873554805f * o : 0.f;
        OUT[(size_t)i * Fd + f] = o;
    }
}

// ---------------- logits + softmax -> assign ----------------
__global__ void k_assign(const float* __restrict__ emb, const float* __restrict__ Wt,
                         const float* __restrict__ bt, float* __restrict__ assign) {
    int i = blockIdx.x, lane = threadIdx.x;  // 64 threads
    float e[4];
    #pragma unroll
    for (int m = 0; m < 4; m++) e[m] = emb[(size_t)i * FOUT + lane + 64 * m];
    float logit[NCLU];
    #pragma unroll
    for (int c = 0; c < NCLU; c++) {
        float p = 0.f;
        #pragma unroll
        for (int m = 0; m < 4; m++) p = fmaf(e[m], Wt[c * FOUT + lane + 64 * m], p);
        #pragma unroll
        for (int off = 32; off > 0; off >>= 1) p += __shfl_xor(p, off);
        logit[c] = p + bt[c];
    }
    float mx = logit[0];
    #pragma unroll
    for (int c = 1; c < NCLU; c++) mx = fmaxf(mx, logit[c]);
    float sum = 0.f, pr[NCLU];
    #pragma unroll
    for (int c = 0; c < NCLU; c++) { pr[c] = expf(logit[c] - mx); sum += pr[c]; }
    float isum = 1.f / sum;
    if (lane < NCLU) {
        float v = 0.f;
        #pragma unroll
        for (int c = 0; c < NCLU; c++) if (lane == c) v = pr[c];
        assign[(size_t)i * NCLU + lane] = v * isum;
    }
}

// ---------------- stats: colA[c], v[c] = sum_i assign[i,c]*deg[i], Esum = sum deg ----------------
__global__ __launch_bounds__(256) void k_stats(const float* __restrict__ assign,
        const float* __restrict__ degf, float* __restrict__ colA,
        float* __restrict__ vvec, float* __restrict__ Esum) {
    __shared__ float sc[NCLU], sv[NCLU], se;
    int tid = threadIdx.x;
    if (tid < NCLU) { sc[tid] = 0.f; sv[tid] = 0.f; }
    if (tid == 0) se = 0.f;
    __syncthreads();
    int i = blockIdx.x * 256 + tid;
    const float d = degf[i];
    const float* ar = assign + (size_t)i * NCLU;
    float ed = d;
    #pragma unroll
    for (int off = 32; off > 0; off >>= 1) ed += __shfl_xor(ed, off);
    if ((tid & 63) == 0) atomicAdd(&se, ed);
    #pragma unroll
    for (int c = 0; c < NCLU; c++) {
        float a = ar[c];
        float av = a * d;
        #pragma unroll
        for (int off = 32; off > 0; off >>= 1) { a += __shfl_xor(a, off); av += __shfl_xor(av, off); }
        if ((tid & 63) == 0) { atomicAdd(&sc[c], a); atomicAdd(&sv[c], av); }
    }
    __syncthreads();
    if (tid < NCLU) { atomicAdd(&colA[tid], sc[tid]); atomicAdd(&vvec[tid], sv[tid]); }
    if (tid == NCLU) atomicAdd(Esum, se);
}

// ---------------- spectral: Tpart[i] (no atomics) ----------------
__global__ __launch_bounds__(256) void k_spectral(const unsigned int* __restrict__ mask,
        const float* __restrict__ assign, const float* __restrict__ colA,
        float* __restrict__ Tpart) {
    __shared__ unsigned short list[LISTCAP];
    __shared__ int cnt_total;
    __shared__ int pos;
    __shared__ float red[4][NCLU];
    int i = blockIdx.x, tid = threadIdx.x;
    if (tid == 0) { cnt_total = 0; pos = 0; }
    __syncthreads();
    unsigned int w = mask[(size_t)i * (NPTS / 32) + tid];
    atomicAdd(&cnt_total, __popc(w));
    __syncthreads();
    const int deg = cnt_total;
    const bool comp = deg > 4096;
    unsigned int wm = comp ? ~w : w;
    if (comp && tid == (i >> 5)) wm &= ~(1u << (i & 31));
    while (wm) {
        int b = __ffs(wm) - 1;
        wm &= wm - 1;
        int pp = atomicAdd(&pos, 1);
        list[pp] = (unsigned short)(tid * 32 + b);
    }
    __syncthreads();
    const int n = comp ? (NPTS - 1 - deg) : deg;
    float yc[NCLU];
    #pragma unroll
    for (int c = 0; c < NCLU; c++) yc[c] = 0.f;
    for (int q = tid; q < n; q += 256) {
        const float* aj = assign + (size_t)list[q] * NCLU;
        #pragma unroll
        for (int c = 0; c < NCLU; c++) yc[c] += aj[c];
    }
    #pragma unroll
    for (int c = 0; c < NCLU; c++) {
        #pragma unroll
        for (int off = 32; off > 0; off >>= 1) yc[c] += __shfl_xor(yc[c], off);
    }
    int wv = tid >> 6, lane = tid & 63;
    if (lane == 0) {
        #pragma unroll
        for (int c = 0; c < NCLU; c++) red[wv][c] = yc[c];
    }
    __syncthreads();
    if (tid == 0) {
        const float* ai = assign + (size_t)i * NCLU;
        float t = 0.f;
        #pragma unroll
        for (int c = 0; c < NCLU; c++) {
            float y = red[0][c] + red[1][c] + red[2][c] + red[3][c];
            if (comp) y = colA[c] - ai[c] - y;
            t = fmaf(y, ai[c], t);
        }
        Tpart[i] = t;
    }
}

// ---------------- final scalar: reduce Tpart + combine ----------------
__global__ __launch_bounds__(256) void k_final(const float* __restrict__ Tpart,
        const float* __restrict__ v, const float* __restrict__ Esum, float* __restrict__ out) {
    __shared__ float red[256];
    int tid = threadIdx.x;
    float s = 0.f;
    for (int i = tid; i < NPTS; i += 256) s += Tpart[i];
    red[tid] = s; __syncthreads();
    for (int off = 128; off > 0; off >>= 1) {
        if (tid < off) red[tid] += red[tid + off];
        __syncthreads();
    }
    if (tid == 0) {
        float E = *Esum;
        float v2 = 0.f;
        for (int c = 0; c < NCLU; c++) v2 += v[c] * v[c];
        float tr_norm = v2 / (2.f * E);
        out[0] = -(red[0] - tr_norm) / (2.f * E);
    }
}

extern "C" void kernel_launch(void* const* d_in, const int* in_sizes, int n_in,
                              void* d_out, int out_size, void* d_ws, size_t ws_size,
                              hipStream_t stream) {
    const float* x     = (const float*)d_in[0];
    const float* W1    = (const float*)d_in[1];
    const float* b1    = (const float*)d_in[2];
    const float* skip1 = (const float*)d_in[3];
    const float* W2    = (const float*)d_in[4];
    const float* b2    = (const float*)d_in[5];
    const float* skip2 = (const float*)d_in[6];
    const float* Wt    = (const float*)d_in[7];
    const float* bt    = (const float*)d_in[8];

    char* ws = (char*)d_ws;
    float* bufA = (float*)ws;                                   // 16 MB  [N x 512]
    float* bufB = (float*)(ws + ((size_t)16 << 20));            // 16 MB  [N x 512]
    unsigned int* mask = (unsigned int*)(ws + ((size_t)32 << 20)); // 8 MB bitmask
    char* p = ws + ((size_t)40 << 20);
    float* sq     = (float*)p; p += NPTS * 4;
    float* degf   = (float*)p; p += NPTS * 4;
    float* inv    = (float*)p; p += NPTS * 4;
    int*   topidx = (int*)p;   p += (size_t)NPTS * KNEI * 4;
    float* assign = (float*)p; p += (size_t)NPTS * NCLU * 4;
    float* Tpart  = (float*)p; p += NPTS * 4;
    // contiguous zero-region: Esum, vvec[10], colA[10], colsum1[512], colsum2[256]
    float* Esum    = (float*)p; p += 4;
    float* vvec    = (float*)p; p += NCLU * 4;
    float* colA    = (float*)p; p += NCLU * 4;
    float* colsum1 = (float*)p; p += FHID * 4;
    float* colsum2 = (float*)p; p += FOUT * 4;

    // xb (bf16 copy of x, 8MB) aliases bufA: dead before k_gemm writes bufA.
    unsigned short* xb = (unsigned short*)bufA;
    // tpv/tpi (2.62 MB each) alias bufB: dead until k_aggregate<1> writes bufB,
    // and consumed by k_topk_merge before that.
    float* tpv = (float*)bufB;
    int*   tpi = (int*)((char*)bufB + ((size_t)4 << 20));

    hipMemsetAsync(mask, 0, (size_t)NPTS * (NPTS / 32) * 4, stream); // 8 MB
    hipMemsetAsync(Esum, 0, (1 + 2 * NCLU + FHID + FOUT) * sizeof(float), stream);

    k_sumsq<<<NPTS, 256, 0, stream>>>(x, sq);
    k_tobf16<<<(NPTS * FIN / 4) / 256, 256, 0, stream>>>(x, xb);
    k_gram_topk<<<(NPTS / GR_ROWS) * GR_CHUNKS, 256, 0, stream>>>(xb, sq, tpv, tpi);
    k_topk_merge<<<NPTS / 256, 256, 0, stream>>>(tpv, tpi, topidx);
    k_set_edges<<<(NPTS * KNEI + 255) / 256, 256, 0, stream>>>(topidx, mask);
    k_degree<<<NPTS, 64, 0, stream>>>(mask, degf, inv);

    // layer 1: P = x @ W1 ; h = act1(P*skip1 + A_hat@P + b1)
    k_gemm<<<dim3(FHID / 64, NPTS / 64), 256, 0, stream>>>(x, W1, bufA, NPTS, FIN, FHID);
    k_colsum<<<dim3(FHID / 256, 64), 256, 0, stream>>>(bufA, colsum1, FHID);
    k_aggregate<1><<<NPTS, 256, 0, stream>>>(bufA, bufB, skip1, b1, inv, mask, colsum1, FHID);
    // layer 2: P2 = h @ W2 ; emb = P2*skip2 + A_hat@P2 + b2
    k_gemm<<<dim3(FOUT / 64, NPTS / 64), 256, 0, stream>>>(bufB, W2, bufA, NPTS, FHID, FOUT);
    k_colsum<<<dim3(FOUT / 256, 64), 256, 0, stream>>>(bufA, colsum2, FOUT);
    k_aggregate<0><<<NPTS, 256, 0, stream>>>(bufA, bufB, skip2, b2, inv, mask, colsum2, FOUT);

    k_assign<<<NPTS, 64, 0, stream>>>(bufB, Wt, bt, assign);
    k_stats<<<NPTS / 256, 256, 0, stream>>>(assign, degf, colA, vvec, Esum);
    k_spectral<<<NPTS, 256, 0, stream>>>(mask, assign, colA, Tpart);
    k_final<<<1, 256, 0, stream>>>(Tpart, vvec, Esum, (float*)d_out);
}

// Round 12
// 720.670 us; speedup vs baseline: 1.9142x; 1.0113x over previous
//
#include <hip/hip_runtime.h>
#include <math.h>
#include <stdint.h>

#define NPTS 8192
#define FIN 512
#define FHID 512
#define FOUT 256
#define NCLU 10
#define KNEI 10
#define LISTCAP 4160   // > 4096 direct cap and > 4095 complement cap

typedef __attribute__((ext_vector_type(4))) float f32x4;
typedef __attribute__((ext_vector_type(8))) short bf16x8;

__device__ __forceinline__ unsigned short bf16_rne(float f) {
    union { float f; unsigned u; } c; c.f = f;
    return (unsigned short)((c.u + 0x7FFFu + ((c.u >> 16) & 1u)) >> 16);
}
__device__ __forceinline__ float bf16_to_f(unsigned short h) {
    union { unsigned u; float f; } c; c.u = ((unsigned)h) << 16;
    return c.f;
}

// ---------------- sum of squares per row ----------------
__global__ void k_sumsq(const float* __restrict__ x, float* __restrict__ sq) {
    int row = blockIdx.x;
    const float* xr = x + (size_t)row * FIN;
    float s = 0.f;
    for (int k = threadIdx.x; k < FIN; k += 256) s += xr[k] * xr[k];
    __shared__ float red[256];
    red[threadIdx.x] = s; __syncthreads();
    for (int off = 128; off > 0; off >>= 1) {
        if (threadIdx.x < off) red[threadIdx.x] += red[threadIdx.x + off];
        __syncthreads();
    }
    if (threadIdx.x == 0) sq[row] = red[0];
}

// ---------------- f32 -> bf16 hi + lo residual (RNE both) ----------------
__global__ void k_split(const float* __restrict__ in, unsigned short* __restrict__ hi,
                        unsigned short* __restrict__ lo) {
    int i = blockIdx.x * 256 + threadIdx.x;   // one float4 per thread
    f32x4 v = reinterpret_cast<const f32x4*>(in)[i];
    ushort4 h, l;
    #pragma unroll
    for (int e = 0; e < 4; e++) {
        unsigned short hb = bf16_rne(v[e]);
        ((unsigned short*)&h)[e] = hb;
        ((unsigned short*)&l)[e] = bf16_rne(v[e] - bf16_to_f(hb));
    }
    reinterpret_cast<ushort4*>(hi)[i] = h;
    reinterpret_cast<ushort4*>(lo)[i] = l;
}

// ---------------- transpose + split W[K][N] -> WT{hi,lo}[N][K] bf16 ----------------
__global__ __launch_bounds__(256) void k_wtrans(const float* __restrict__ W,
        unsigned short* __restrict__ TH, unsigned short* __restrict__ TL, int K, int N) {
    __shared__ float t[32][33];
    int k0 = blockIdx.y * 32, n0 = blockIdx.x * 32;
    int ln = threadIdx.x & 31, lt = threadIdx.x >> 5;   // 32 x 8
    #pragma unroll
    for (int q = 0; q < 4; q++)
        t[lt + q * 8][ln] = W[(size_t)(k0 + lt + q * 8) * N + n0 + ln];
    __syncthreads();
    #pragma unroll
    for (int q = 0; q < 4; q++) {
        float v = t[ln][lt + q * 8];
        unsigned short hb = bf16_rne(v);
        size_t o = (size_t)(n0 + lt + q * 8) * K + k0 + ln;
        TH[o] = hb;
        TL[o] = bf16_rne(v - bf16_to_f(hb));
    }
}

// ---------------- fused MFMA gram + exp + per-row partial top-10 ----------------
// grid: 512 = 64 row-groups x 8 col-chunks. Block (512 thr, 8 waves) owns 128
// rows (16/wave, A in registers); B (128 cols x 64 k) double-buffered in LDS via
// register prefetch. Top-k scanned directly from accumulators. B-issue traffic
// = (8192/128) x 8MB = 512 MB (half of GR_ROWS=64).
#define GR_ROWS 128
#define GR_TW 128
#define GR_CHUNKS 8
#define GR_CHUNK_COLS (NPTS / GR_CHUNKS)            // 1024
#define GR_TILES_PER_CHUNK (GR_CHUNK_COLS / GR_TW)  // 8
#define GR_STEPS (GR_TILES_PER_CHUNK * 8)           // 64 k-steps

__global__ __launch_bounds__(512, 2) void k_gram_topk(
    const unsigned short* __restrict__ xb, const float* __restrict__ sq,
    float* __restrict__ tpv, int* __restrict__ tpi)
{
    __shared__ short Bl[2][128][64];              // 32 KB double-buffered B
    __shared__ float tval[GR_ROWS][KNEI];
    __shared__ int   tidxs[GR_ROWS][KNEI];

    const int tid  = threadIdx.x;
    const int lane = tid & 63;
    const int wv   = tid >> 6;            // 0..7
    const int rg   = blockIdx.x >> 3;
    const int ch   = blockIdx.x & 7;
    const int r0   = rg * GR_ROWS;
    const int cbase = ch * GR_CHUNK_COLS;

    for (int e = tid; e < GR_ROWS * KNEI; e += 512) {
        tval[e / KNEI][e % KNEI] = -INFINITY;
        tidxs[e / KNEI][e % KNEI] = 0x7fffffff;
    }

    // A fragments: wave wv owns rows r0+wv*16 .. +16, full K in registers
    const int arow  = r0 + wv * 16 + (lane & 15);
    const int akoff = (lane >> 4) * 8;
    bf16x8 afr[16];
    #pragma unroll
    for (int ks = 0; ks < 16; ks++)
        afr[ks] = *reinterpret_cast<const bf16x8*>(xb + (size_t)arow * FIN + ks * 32 + akoff);

    float si_r[4];
    #pragma unroll
    for (int r = 0; r < 4; r++) si_r[r] = sq[r0 + wv * 16 + (lane >> 4) * 4 + r];

    const int stg_row = tid >> 2, stg_seg = tid & 3;   // 4 threads/row, 2 granules each

    // prefetch step 0 into registers, write buf 0
    bf16x8 pre[2];
    {
        const unsigned short* src = xb + (size_t)(cbase + stg_row) * FIN + stg_seg * 16;
        #pragma unroll
        for (int q = 0; q < 2; q++) pre[q] = *reinterpret_cast<const bf16x8*>(src + q * 8);
        #pragma unroll
        for (int q = 0; q < 2; q++) {
            int g = stg_seg * 2 + q;
            *reinterpret_cast<bf16x8*>(&Bl[0][stg_row][(g ^ (stg_row & 7)) * 8]) = pre[q];
        }
    }
    __syncthreads();   // buf0 ready; also covers tval init

    f32x4 acc[8];
    for (int u = 0; u < GR_STEPS; ++u) {
        const int t  = u >> 3, kc = u & 7;
        const int c0 = cbase + t * GR_TW;
        const int cur = u & 1;

        if (kc == 0) {
            #pragma unroll
            for (int ct = 0; ct < 8; ct++) acc[ct] = (f32x4){0.f, 0.f, 0.f, 0.f};
        }

        // issue next step's global loads (latency hides under MFMA + scan)
        if (u < GR_STEPS - 1) {
            const int u2 = u + 1, t2 = u2 >> 3, kc2 = u2 & 7;
            const unsigned short* src = xb + (size_t)(cbase + t2 * GR_TW + stg_row) * FIN + kc2 * 64 + stg_seg * 16;
            #pragma unroll
            for (int q = 0; q < 2; q++) pre[q] = *reinterpret_cast<const bf16x8*>(src + q * 8);
        }

        // MFMA from Bl[cur]
        #pragma unroll
        for (int ksl = 0; ksl < 2; ++ksl) {
            #pragma unroll
            for (int ct = 0; ct < 8; ct++) {
                const int cl = ct * 16 + (lane & 15);
                const int q = ksl * 4 + (lane >> 4);
                bf16x8 bfr = *reinterpret_cast<const bf16x8*>(&Bl[cur][cl][(q ^ (cl & 7)) * 8]);
                acc[ct] = __builtin_amdgcn_mfma_f32_16x16x32_bf16(afr[kc * 2 + ksl], bfr, acc[ct], 0, 0, 0);
            }
        }

        // tile complete: scan top-10 directly from accumulators (wave-local)
        if (kc == 7) {
            #pragma unroll
            for (int ct = 0; ct < 8; ct++) {
                const int gj  = c0 + ct * 16 + (lane & 15);
                const float sjv = sq[gj];
                float sv[4];
                #pragma unroll
                for (int r = 0; r < 4; r++) {
                    const int gi = r0 + wv * 16 + (lane >> 4) * 4 + r;
                    const float d2 = si_r[r] + sjv - 2.f * acc[ct][r];
                    sv[r] = (gj == gi) ? -INFINITY : expf(-d2 * 0.5f);
                }
                #pragma unroll
                for (int r = 0; r < 4; r++) {
                    const int myrow = wv * 16 + (lane >> 4) * 4 + r;
                    float t9 = tval[myrow][KNEI - 1];
                    int   i9 = tidxs[myrow][KNEI - 1];
                    unsigned long long bal = __ballot(sv[r] > t9 || (sv[r] == t9 && gj < i9));
                    while (bal) {
                        int l = __ffsll(bal) - 1;
                        bal &= bal - 1;
                        float cv = __shfl(sv[r], l);
                        int   cj = c0 + ct * 16 + (l & 15);
                        int   rfull = wv * 16 + (l >> 4) * 4 + r;
                        if (lane == 0) {
                            float a9 = tval[rfull][KNEI - 1];
                            int   i9b = tidxs[rfull][KNEI - 1];
                            if (cv > a9 || (cv == a9 && cj < i9b)) {
                                int pp = KNEI - 1;
                                tval[rfull][pp] = cv; tidxs[rfull][pp] = cj;
                                while (pp > 0) {
                                    float pv = tval[rfull][pp - 1]; int pi = tidxs[rfull][pp - 1];
                                    if (cv > pv || (cv == pv && cj < pi)) {
                                        tval[rfull][pp] = pv; tidxs[rfull][pp] = pi;
                                        tval[rfull][pp - 1] = cv; tidxs[rfull][pp - 1] = cj;
                                        --pp;
                                    } else break;
                                }
                            }
                        }
                    }
                }
            }
        }

        // write prefetched step into the other buffer
        if (u < GR_STEPS - 1) {
            #pragma unroll
            for (int q = 0; q < 2; q++) {
                int g = stg_seg * 2 + q;
                *reinterpret_cast<bf16x8*>(&Bl[cur ^ 1][stg_row][(g ^ (stg_row & 7)) * 8]) = pre[q];
            }
        }
        __syncthreads();
    }

    for (int e = tid; e < GR_ROWS * KNEI; e += 512) {
        int r = e / KNEI, m = e % KNEI;
        size_t o = (((size_t)(r0 + r) * GR_CHUNKS) + ch) * KNEI + m;
        tpv[o] = tval[r][m];
        tpi[o] = tidxs[r][m];
    }
}

// ---------------- merge 8 partial top-10 lists per row ----------------
__global__ __launch_bounds__(256) void k_topk_merge(const float* __restrict__ tpv,
        const int* __restrict__ tpi, int* __restrict__ topidx) {
    int r = blockIdx.x * 256 + threadIdx.x;
    int p[GR_CHUNKS];
    #pragma unroll
    for (int c = 0; c < GR_CHUNKS; c++) p[c] = 0;
    #pragma unroll
    for (int m = 0; m < KNEI; m++) {
        float bv = -INFINITY; int bi = 0x7fffffff; int bc = 0;
        #pragma unroll
        for (int c = 0; c < GR_CHUNKS; c++) {
            if (p[c] < KNEI) {
                size_t o = (((size_t)r * GR_CHUNKS) + c) * KNEI + p[c];
                float v = tpv[o];
                int idx = tpi[o];
                if (v > bv || (v == bv && idx < bi)) { bv = v; bi = idx; bc = c; }
            }
        }
        topidx[(size_t)r * KNEI + m] = bi;
        p[bc]++;
    }
}

// ---------------- build symmetric adjacency bitmask ----------------
__global__ void k_set_edges(const int* __restrict__ topidx, unsigned int* __restrict__ mask) {
    int t = blockIdx.x * 256 + threadIdx.x;
    if (t >= NPTS * KNEI) return;
    int i = t / KNEI;
    int j = topidx[t];
    atomicOr(&mask[(size_t)i * (NPTS / 32) + (j >> 5)], 1u << (j & 31));
    atomicOr(&mask[(size_t)j * (NPTS / 32) + (i >> 5)], 1u << (i & 31));
}

// ---------------- degree, inv ----------------
__global__ void k_degree(const unsigned int* __restrict__ mask, float* __restrict__ degf,
                         float* __restrict__ inv) {
    int i = blockIdx.x, lane = threadIdx.x;  // 64 threads
    int c = 0;
    for (int w = lane; w < NPTS / 32; w += 64) c += __popc(mask[(size_t)i * (NPTS / 32) + w]);
    for (int off = 32; off > 0; off >>= 1) c += __shfl_xor(c, off);
    if (lane == 0) {
        float d = (float)c;
        degf[i] = d;
        inv[i] = (c > 0) ? 1.0f / d : 0.0f;
    }
}

// ---------------- bf16x3 MFMA GEMM: C[M,N] = A[M,K] @ B[K,N] ----------------
// A given as hi/lo bf16 [M][K]; B given pre-transposed hi/lo bf16 [N][K].
// (Ahi+Alo)(Bhi+Blo) ~= AhiBhi + AhiBlo + AloBhi  (AloBlo ~ 2^-18, dropped)
__global__ __launch_bounds__(256) void k_gemm_mfma(
    const unsigned short* __restrict__ Ahi, const unsigned short* __restrict__ Alo,
    const unsigned short* __restrict__ BThi, const unsigned short* __restrict__ BTlo,
    float* __restrict__ C, int M, int K, int N)
{
    const int tid = threadIdx.x, lane = tid & 63, wv = tid >> 6;
    const int bx = blockIdx.x, by = blockIdx.y;
    const int arow = by * 64 + wv * 16 + (lane & 15);
    const int koff = (lane >> 4) * 8;

    f32x4 acc[8];
    #pragma unroll
    for (int ct = 0; ct < 8; ct++) acc[ct] = (f32x4){0.f, 0.f, 0.f, 0.f};

    for (int kb = 0; kb < K; kb += 128) {
        bf16x8 ah[4], al[4];
        #pragma unroll
        for (int ksl = 0; ksl < 4; ksl++) {
            ah[ksl] = *reinterpret_cast<const bf16x8*>(Ahi + (size_t)arow * K + kb + ksl * 32 + koff);
            al[ksl] = *reinterpret_cast<const bf16x8*>(Alo + (size_t)arow * K + kb + ksl * 32 + koff);
        }
        #pragma unroll
        for (int ksl = 0; ksl < 4; ksl++) {
            #pragma unroll
            for (int ct = 0; ct < 8; ct++) {
                const int n = bx * 128 + ct * 16 + (lane & 15);
                bf16x8 bh = *reinterpret_cast<const bf16x8*>(BThi + (size_t)n * K + kb + ksl * 32 + koff);
                bf16x8 bl = *reinterpret_cast<const bf16x8*>(BTlo + (size_t)n * K + kb + ksl * 32 + koff);
                acc[ct] = __builtin_amdgcn_mfma_f32_16x16x32_bf16(ah[ksl], bh, acc[ct], 0, 0, 0);
                acc[ct] = __builtin_amdgcn_mfma_f32_16x16x32_bf16(ah[ksl], bl, acc[ct], 0, 0, 0);
                acc[ct] = __builtin_amdgcn_mfma_f32_16x16x32_bf16(al[ksl], bh, acc[ct], 0, 0, 0);
            }
        }
    }
    #pragma unroll
    for (int ct = 0; ct < 8; ct++) {
        const int col = bx * 128 + ct * 16 + (lane & 15);
        #pragma unroll
        for (int r = 0; r < 4; r++) {
            const int row = by * 64 + wv * 16 + (lane >> 4) * 4 + r;
            C[(size_t)row * N + col] = acc[ct][r];
        }
    }
}

// ---------------- column sums of P: colsum[f] = sum_j P[j,f] ----------------
__global__ __launch_bounds__(256) void k_colsum(const float* __restrict__ P, float* __restrict__ colsum, int Fd) {
    int f = blockIdx.x * 256 + threadIdx.x;
    int r0 = blockIdx.y * (NPTS / 64);
    float s = 0.f;
    for (int r = 0; r < NPTS / 64; r++) s += P[(size_t)(r0 + r) * Fd + f];
    atomicAdd(&colsum[f], s);
}

// ---------------- aggregation + skip + bias + activation (dual-mode) ----------------
template <int ACT>
__global__ __launch_bounds__(256) void k_aggregate(const float* __restrict__ P, float* __restrict__ OUT,
        const float* __restrict__ skip, const float* __restrict__ bias,
        const float* __restrict__ inv, const unsigned int* __restrict__ mask,
        const float* __restrict__ colsum, int Fd) {
    __shared__ unsigned short list[LISTCAP];
    __shared__ int cnt_total;
    __shared__ int pos;
    int i = blockIdx.x, tid = threadIdx.x;
    if (tid == 0) { cnt_total = 0; pos = 0; }
    __syncthreads();
    unsigned int w = mask[(size_t)i * (NPTS / 32) + tid];  // 256 words, 256 threads
    atomicAdd(&cnt_total, __popc(w));
    __syncthreads();
    const int deg = cnt_total;
    const bool comp = deg > 4096;
    unsigned int wm = comp ? ~w : w;
    if (comp && tid == (i >> 5)) wm &= ~(1u << (i & 31));   // exclude self from complement
    while (wm) {
        int b = __ffs(wm) - 1;
        wm &= wm - 1;
        int pp = atomicAdd(&pos, 1);
        list[pp] = (unsigned short)(tid * 32 + b);
    }
    __syncthreads();
    const int n = comp ? (NPTS - 1 - deg) : deg;
    const float vinv = inv[i];
    for (int f = tid; f < Fd; f += 256) {
        float s = 0.f;
        for (int q = 0; q < n; q++) s += P[(size_t)list[q] * Fd + f];
        const float pif = P[(size_t)i * Fd + f];
        const float nb = comp ? (colsum[f] - pif - s) : s;
        float o = pif * skip[f] + vinv * nb + bias[f];
        if (ACT == 1) o = (o > 0.f) ? 1.0507009873554805f * o : 0.f;
        OUT[(size_t)i * Fd + f] = o;
    }
}

// ---------------- logits + softmax -> assign ----------------
__global__ void k_assign(const float* __restrict__ emb, const float* __restrict__ Wt,
                         const float* __restrict__ bt, float* __restrict__ assign) {
    int i = blockIdx.x, lane = threadIdx.x;  // 64 threads
    float e[4];
    #pragma unroll
    for (int m = 0; m < 4; m++) e[m] = emb[(size_t)i * FOUT + lane + 64 * m];
    float logit[NCLU];
    #pragma unroll
    for (int c = 0; c < NCLU; c++) {
        float p = 0.f;
        #pragma unroll
        for (int m = 0; m < 4; m++) p = fmaf(e[m], Wt[c * FOUT + lane + 64 * m], p);
        #pragma unroll
        for (int off = 32; off > 0; off >>= 1) p += __shfl_xor(p, off);
        logit[c] = p + bt[c];
    }
    float mx = logit[0];
    #pragma unroll
    for (int c = 1; c < NCLU; c++) mx = fmaxf(mx, logit[c]);
    float sum = 0.f, pr[NCLU];
    #pragma unroll
    for (int c = 0; c < NCLU; c++) { pr[c] = expf(logit[c] - mx); sum += pr[c]; }
    float isum = 1.f / sum;
    if (lane < NCLU) {
        float v = 0.f;
        #pragma unroll
        for (int c = 0; c < NCLU; c++) if (lane == c) v = pr[c];
        assign[(size_t)i * NCLU + lane] = v * isum;
    }
}

// ---------------- stats: colA[c], v[c] = sum_i assign[i,c]*deg[i], Esum = sum deg ----------------
__global__ __launch_bounds__(256) void k_stats(const float* __restrict__ assign,
        const float* __restrict__ degf, float* __restrict__ colA,
        float* __restrict__ vvec, float* __restrict__ Esum) {
    __shared__ float sc[NCLU], sv[NCLU], se;
    int tid = threadIdx.x;
    if (tid < NCLU) { sc[tid] = 0.f; sv[tid] = 0.f; }
    if (tid == 0) se = 0.f;
    __syncthreads();
    int i = blockIdx.x * 256 + tid;
    const float d = degf[i];
    const float* ar = assign + (size_t)i * NCLU;
    float ed = d;
    #pragma unroll
    for (int off = 32; off > 0; off >>= 1) ed += __shfl_xor(ed, off);
    if ((tid & 63) == 0) atomicAdd(&se, ed);
    #pragma unroll
    for (int c = 0; c < NCLU; c++) {
        float a = ar[c];
        float av = a * d;
        #pragma unroll
        for (int off = 32; off > 0; off >>= 1) { a += __shfl_xor(a, off); av += __shfl_xor(av, off); }
        if ((tid & 63) == 0) { atomicAdd(&sc[c], a); atomicAdd(&sv[c], av); }
    }
    __syncthreads();
    if (tid < NCLU) { atomicAdd(&colA[tid], sc[tid]); atomicAdd(&vvec[tid], sv[tid]); }
    if (tid == NCLU) atomicAdd(Esum, se);
}

// ---------------- spectral: Tpart[i] (no atomics) ----------------
__global__ __launch_bounds__(256) void k_spectral(const unsigned int* __restrict__ mask,
        const float* __restrict__ assign, const float* __restrict__ colA,
        float* __restrict__ Tpart) {
    __shared__ unsigned short list[LISTCAP];
    __shared__ int cnt_total;
    __shared__ int pos;
    __shared__ float red[4][NCLU];
    int i = blockIdx.x, tid = threadIdx.x;
    if (tid == 0) { cnt_total = 0; pos = 0; }
    __syncthreads();
    unsigned int w = mask[(size_t)i * (NPTS / 32) + tid];
    atomicAdd(&cnt_total, __popc(w));
    __syncthreads();
    const int deg = cnt_total;
    const bool comp = deg > 4096;
    unsigned int wm = comp ? ~w : w;
    if (comp && tid == (i >> 5)) wm &= ~(1u << (i & 31));
    while (wm) {
        int b = __ffs(wm) - 1;
        wm &= wm - 1;
        int pp = atomicAdd(&pos, 1);
        list[pp] = (unsigned short)(tid * 32 + b);
    }
    __syncthreads();
    const int n = comp ? (NPTS - 1 - deg) : deg;
    float yc[NCLU];
    #pragma unroll
    for (int c = 0; c < NCLU; c++) yc[c] = 0.f;
    for (int q = tid; q < n; q += 256) {
        const float* aj = assign + (size_t)list[q] * NCLU;
        #pragma unroll
        for (int c = 0; c < NCLU; c++) yc[c] += aj[c];
    }
    #pragma unroll
    for (int c = 0; c < NCLU; c++) {
        #pragma unroll
        for (int off = 32; off > 0; off >>= 1) yc[c] += __shfl_xor(yc[c], off);
    }
    int wv = tid >> 6, lane = tid & 63;
    if (lane == 0) {
        #pragma unroll
        for (int c = 0; c < NCLU; c++) red[wv][c] = yc[c];
    }
    __syncthreads();
    if (tid == 0) {
        const float* ai = assign + (size_t)i * NCLU;
        float t = 0.f;
        #pragma unroll
        for (int c = 0; c < NCLU; c++) {
            float y = red[0][c] + red[1][c] + red[2][c] + red[3][c];
            if (comp) y = colA[c] - ai[c] - y;
            t = fmaf(y, ai[c], t);
        }
        Tpart[i] = t;
    }
}

// ---------------- final scalar: reduce Tpart + combine ----------------
__global__ __launch_bounds__(256) void k_final(const float* __restrict__ Tpart,
        const float* __restrict__ v, const float* __restrict__ Esum, float* __restrict__ out) {
    __shared__ float red[256];
    int tid = threadIdx.x;
    float s = 0.f;
    for (int i = tid; i < NPTS; i += 256) s += Tpart[i];
    red[tid] = s; __syncthreads();
    for (int off = 128; off > 0; off >>= 1) {
        if (tid < off) red[tid] += red[tid + off];
        __syncthreads();
    }
    if (tid == 0) {
        float E = *Esum;
        float v2 = 0.f;
        for (int c = 0; c < NCLU; c++) v2 += v[c] * v[c];
        float tr_norm = v2 / (2.f * E);
        out[0] = -(red[0] - tr_norm) / (2.f * E);
    }
}

extern "C" void kernel_launch(void* const* d_in, const int* in_sizes, int n_in,
                              void* d_out, int out_size, void* d_ws, size_t ws_size,
                              hipStream_t stream) {
    const float* x     = (const float*)d_in[0];
    const float* W1    = (const float*)d_in[1];
    const float* b1    = (const float*)d_in[2];
    const float* skip1 = (const float*)d_in[3];
    const float* W2    = (const float*)d_in[4];
    const float* b2    = (const float*)d_in[5];
    const float* skip2 = (const float*)d_in[6];
    const float* Wt    = (const float*)d_in[7];
    const float* bt    = (const float*)d_in[8];

    char* ws = (char*)d_ws;
    float* bufA = (float*)ws;                                      // 16 MB
    float* bufB = (float*)(ws + ((size_t)16 << 20));               // 16 MB
    unsigned int* mask = (unsigned int*)(ws + ((size_t)32 << 20)); // 8 MB bitmask
    unsigned short* xlo = (unsigned short*)(ws + ((size_t)40 << 20)); // 8 MB (lo of x, then lo of h)
    char* p = ws + ((size_t)48 << 20);
    float* sq     = (float*)p; p += NPTS * 4;
    float* degf   = (float*)p; p += NPTS * 4;
    float* inv    = (float*)p; p += NPTS * 4;
    int*   topidx = (int*)p;   p += (size_t)NPTS * KNEI * 4;
    float* assign = (float*)p; p += (size_t)NPTS * NCLU * 4;
    float* Tpart  = (float*)p; p += NPTS * 4;
    // contiguous zero-region: Esum, vvec[10], colA[10], colsum1[512], colsum2[256]
    float* Esum    = (float*)p; p += 4;
    float* vvec    = (float*)p; p += NCLU * 4;
    float* colA    = (float*)p; p += NCLU * 4;
    float* colsum1 = (float*)p; p += FHID * 4;
    float* colsum2 = (float*)p; p += FOUT * 4;
    unsigned short* WT1hi = (unsigned short*)p; p += (size_t)FHID * FIN * 2;   // [512][512]
    unsigned short* WT1lo = (unsigned short*)p; p += (size_t)FHID * FIN * 2;
    unsigned short* WT2hi = (unsigned short*)p; p += (size_t)FOUT * FHID * 2;  // [256][512]
    unsigned short* WT2lo = (unsigned short*)p; p += (size_t)FOUT * FHID * 2;

    // xb (bf16 hi of x, 8MB) aliases bufA[0:8MB]: dead before gemm1 writes bufB/aggregate writes bufA.
    unsigned short* xb = (unsigned short*)bufA;
    // tpv/tpi alias bufB: consumed by k_topk_merge before gemm1 overwrites bufB.
    float* tpv = (float*)bufB;
    int*   tpi = (int*)((char*)bufB + ((size_t)4 << 20));
    // layer-2 split targets: h_hi -> bufB[0:8MB] (P1 dead), h_lo -> xlo; P2 -> bufB[8:16MB]
    unsigned short* hhi = (unsigned short*)bufB;
    float* P2 = bufB + ((size_t)2 << 20);   // 8 MB offset in floats

    hipMemsetAsync(mask, 0, (size_t)NPTS * (NPTS / 32) * 4, stream); // 8 MB
    hipMemsetAsync(Esum, 0, (1 + 2 * NCLU + FHID + FOUT) * sizeof(float), stream);

    k_sumsq<<<NPTS, 256, 0, stream>>>(x, sq);
    k_split<<<(NPTS * FIN / 4) / 256, 256, 0, stream>>>(x, xb, xlo);
    k_wtrans<<<dim3(FHID / 32, FIN / 32), 256, 0, stream>>>(W1, WT1hi, WT1lo, FIN, FHID);
    k_wtrans<<<dim3(FOUT / 32, FHID / 32), 256, 0, stream>>>(W2, WT2hi, WT2lo, FHID, FOUT);

    k_gram_topk<<<(NPTS / GR_ROWS) * GR_CHUNKS, 512, 0, stream>>>(xb, sq, tpv, tpi);
    k_topk_merge<<<NPTS / 256, 256, 0, stream>>>(tpv, tpi, topidx);
    k_set_edges<<<(NPTS * KNEI + 255) / 256, 256, 0, stream>>>(topidx, mask);
    k_degree<<<NPTS, 64, 0, stream>>>(mask, degf, inv);

    // layer 1: P1 = x @ W1 (bf16x3 MFMA) -> bufB ; h = act1(...) -> bufA
    k_gemm_mfma<<<dim3(FHID / 128, NPTS / 64), 256, 0, stream>>>(xb, xlo, WT1hi, WT1lo, bufB, NPTS, FIN, FHID);
    k_colsum<<<dim3(FHID / 256, 64), 256, 0, stream>>>(bufB, colsum1, FHID);
    k_aggregate<1><<<NPTS, 256, 0, stream>>>(bufB, bufA, skip1, b1, inv, mask, colsum1, FHID);

    // layer 2: split h; P2 = h @ W2 -> bufB[8:16MB] ; emb -> bufA
    k_split<<<(NPTS * FHID / 4) / 256, 256, 0, stream>>>(bufA, hhi, xlo);
    k_gemm_mfma<<<dim3(FOUT / 128, NPTS / 64), 256, 0, stream>>>(hhi, xlo, WT2hi, WT2lo, P2, NPTS, FHID, FOUT);
    k_colsum<<<dim3(FOUT / 256, 64), 256, 0, stream>>>(P2, colsum2, FOUT);
    k_aggregate<0><<<NPTS, 256, 0, stream>>>(P2, bufA, skip2, b2, inv, mask, colsum2, FOUT);

    k_assign<<<NPTS, 64, 0, stream>>>(bufA, Wt, bt, assign);
    k_stats<<<NPTS / 256, 256, 0, stream>>>(assign, degf, colA, vvec, Esum);
    k_spectral<<<NPTS, 256, 0, stream>>>(mask, assign, colA, Tpart);
    k_final<<<1, 256, 0, stream>>>(Tpart, vvec, Esum, (float*)d_out);
}

// Round 13
// 642.901 us; speedup vs baseline: 2.1458x; 1.1210x over previous
//
#include <hip/hip_runtime.h>
#include <math.h>
#include <stdint.h>

#define NPTS 8192
#define FIN 512
#define FHID 512
#define FOUT 256
#define NCLU 10
#define KNEI 10
#define LISTCAP 4160   // > 4096 direct cap and > 4095 complement cap

typedef __attribute__((ext_vector_type(4))) float f32x4;
typedef __attribute__((ext_vector_type(8))) short bf16x8;

__device__ __forceinline__ unsigned short bf16_rne(float f) {
    union { float f; unsigned u; } c; c.f = f;
    return (unsigned short)((c.u + 0x7FFFu + ((c.u >> 16) & 1u)) >> 16);
}
__device__ __forceinline__ float bf16_to_f(unsigned short h) {
    union { unsigned u; float f; } c; c.u = ((unsigned)h) << 16;
    return c.f;
}

// ---------------- sum of squares per row ----------------
__global__ void k_sumsq(const float* __restrict__ x, float* __restrict__ sq) {
    int row = blockIdx.x;
    const float* xr = x + (size_t)row * FIN;
    float s = 0.f;
    for (int k = threadIdx.x; k < FIN; k += 256) s += xr[k] * xr[k];
    __shared__ float red[256];
    red[threadIdx.x] = s; __syncthreads();
    for (int off = 128; off > 0; off >>= 1) {
        if (threadIdx.x < off) red[threadIdx.x] += red[threadIdx.x + off];
        __syncthreads();
    }
    if (threadIdx.x == 0) sq[row] = red[0];
}

// ---------------- f32 -> bf16 hi + lo residual (RNE both) ----------------
__global__ void k_split(const float* __restrict__ in, unsigned short* __restrict__ hi,
                        unsigned short* __restrict__ lo) {
    int i = blockIdx.x * 256 + threadIdx.x;   // one float4 per thread
    f32x4 v = reinterpret_cast<const f32x4*>(in)[i];
    ushort4 h, l;
    #pragma unroll
    for (int e = 0; e < 4; e++) {
        unsigned short hb = bf16_rne(v[e]);
        ((unsigned short*)&h)[e] = hb;
        ((unsigned short*)&l)[e] = bf16_rne(v[e] - bf16_to_f(hb));
    }
    reinterpret_cast<ushort4*>(hi)[i] = h;
    reinterpret_cast<ushort4*>(lo)[i] = l;
}

// ---------------- transpose + split W[K][N] -> WT{hi,lo}[N][K] bf16 ----------------
__global__ __launch_bounds__(256) void k_wtrans(const float* __restrict__ W,
        unsigned short* __restrict__ TH, unsigned short* __restrict__ TL, int K, int N) {
    __shared__ float t[32][33];
    int k0 = blockIdx.y * 32, n0 = blockIdx.x * 32;
    int ln = threadIdx.x & 31, lt = threadIdx.x >> 5;   // 32 x 8
    #pragma unroll
    for (int q = 0; q < 4; q++)
        t[lt + q * 8][ln] = W[(size_t)(k0 + lt + q * 8) * N + n0 + ln];
    __syncthreads();
    #pragma unroll
    for (int q = 0; q < 4; q++) {
        float v = t[ln][lt + q * 8];
        unsigned short hb = bf16_rne(v);
        size_t o = (size_t)(n0 + lt + q * 8) * K + k0 + ln;
        TH[o] = hb;
        TL[o] = bf16_rne(v - bf16_to_f(hb));
    }
}

// ---------------- fused MFMA gram + exp + per-row partial top-10 ----------------
// grid: 512 = 64 row-groups x 8 col-chunks. Block (512 thr, 8 waves) owns 128
// rows (16/wave, A in registers); B (128 cols x 64 k) double-buffered in LDS via
// register prefetch. Top-k: bounded iterative extraction (find-max via shfl
// reduce, <=10 LDS inserts per row per tile) -- no ballot storm.
#define GR_ROWS 128
#define GR_TW 128
#define GR_CHUNKS 8
#define GR_CHUNK_COLS (NPTS / GR_CHUNKS)            // 1024
#define GR_TILES_PER_CHUNK (GR_CHUNK_COLS / GR_TW)  // 8
#define GR_STEPS (GR_TILES_PER_CHUNK * 8)           // 64 k-steps

__global__ __launch_bounds__(512, 2) void k_gram_topk(
    const unsigned short* __restrict__ xb, const float* __restrict__ sq,
    float* __restrict__ tpv, int* __restrict__ tpi)
{
    __shared__ short Bl[2][128][64];              // 32 KB double-buffered B
    __shared__ float tval[GR_ROWS][KNEI];
    __shared__ int   tidxs[GR_ROWS][KNEI];

    const int tid  = threadIdx.x;
    const int lane = tid & 63;
    const int wv   = tid >> 6;            // 0..7
    const int rg   = blockIdx.x >> 3;
    const int ch   = blockIdx.x & 7;
    const int r0   = rg * GR_ROWS;
    const int cbase = ch * GR_CHUNK_COLS;

    for (int e = tid; e < GR_ROWS * KNEI; e += 512) {
        tval[e / KNEI][e % KNEI] = -INFINITY;
        tidxs[e / KNEI][e % KNEI] = 0x7fffffff;
    }

    // A fragments: wave wv owns rows r0+wv*16 .. +16, full K in registers
    const int arow  = r0 + wv * 16 + (lane & 15);
    const int akoff = (lane >> 4) * 8;
    bf16x8 afr[16];
    #pragma unroll
    for (int ks = 0; ks < 16; ks++)
        afr[ks] = *reinterpret_cast<const bf16x8*>(xb + (size_t)arow * FIN + ks * 32 + akoff);

    float si_r[4];
    #pragma unroll
    for (int r = 0; r < 4; r++) si_r[r] = sq[r0 + wv * 16 + (lane >> 4) * 4 + r];

    const int stg_row = tid >> 2, stg_seg = tid & 3;   // 4 threads/row, 2 granules each

    // prefetch step 0 into registers, write buf 0
    bf16x8 pre[2];
    {
        const unsigned short* src = xb + (size_t)(cbase + stg_row) * FIN + stg_seg * 16;
        #pragma unroll
        for (int q = 0; q < 2; q++) pre[q] = *reinterpret_cast<const bf16x8*>(src + q * 8);
        #pragma unroll
        for (int q = 0; q < 2; q++) {
            int g = stg_seg * 2 + q;
            *reinterpret_cast<bf16x8*>(&Bl[0][stg_row][(g ^ (stg_row & 7)) * 8]) = pre[q];
        }
    }
    __syncthreads();   // buf0 ready; also covers tval init

    f32x4 acc[8];
    for (int u = 0; u < GR_STEPS; ++u) {
        const int t  = u >> 3, kc = u & 7;
        const int c0 = cbase + t * GR_TW;
        const int cur = u & 1;

        if (kc == 0) {
            #pragma unroll
            for (int ct = 0; ct < 8; ct++) acc[ct] = (f32x4){0.f, 0.f, 0.f, 0.f};
        }

        // issue next step's global loads (latency hides under MFMA + scan)
        if (u < GR_STEPS - 1) {
            const int u2 = u + 1, t2 = u2 >> 3, kc2 = u2 & 7;
            const unsigned short* src = xb + (size_t)(cbase + t2 * GR_TW + stg_row) * FIN + kc2 * 64 + stg_seg * 16;
            #pragma unroll
            for (int q = 0; q < 2; q++) pre[q] = *reinterpret_cast<const bf16x8*>(src + q * 8);
        }

        // MFMA from Bl[cur]
        #pragma unroll
        for (int ksl = 0; ksl < 2; ++ksl) {
            #pragma unroll
            for (int ct = 0; ct < 8; ct++) {
                const int cl = ct * 16 + (lane & 15);
                const int q = ksl * 4 + (lane >> 4);
                bf16x8 bfr = *reinterpret_cast<const bf16x8*>(&Bl[cur][cl][(q ^ (cl & 7)) * 8]);
                acc[ct] = __builtin_amdgcn_mfma_f32_16x16x32_bf16(afr[kc * 2 + ksl], bfr, acc[ct], 0, 0, 0);
            }
        }

        // tile complete: bounded top-10 extraction from accumulators
        if (kc == 7) {
            float sjv[8];
            #pragma unroll
            for (int ct = 0; ct < 8; ct++) sjv[ct] = sq[c0 + ct * 16 + (lane & 15)];

            #pragma unroll
            for (int r = 0; r < 4; ++r) {
                const int row_g = wv * 16 + (lane >> 4) * 4 + r;
                const int gi = r0 + row_g;
                float cvv[8];
                #pragma unroll
                for (int ct = 0; ct < 8; ct++) {
                    const int gj = c0 + ct * 16 + (lane & 15);
                    const float d2 = si_r[r] + sjv[ct] - 2.f * acc[ct][r];
                    cvv[ct] = (gj == gi) ? -INFINITY : expf(-d2 * 0.5f);
                }
                float lv = INFINITY; int lj = -1;   // last extracted (total order cursor)
                bool done = false;
                #pragma unroll 1
                for (int m = 0; m < KNEI; ++m) {
                    // local best eligible candidate among this lane's 8
                    float bv = -INFINITY; int bj = 0x7fffffff;
                    #pragma unroll
                    for (int ct = 0; ct < 8; ct++) {
                        const int j = c0 + ct * 16 + (lane & 15);
                        const float v = cvv[ct];
                        bool elig = (!done) && (v < lv || (v == lv && j > lj));
                        bool better = elig && (v > bv || (v == bv && j < bj));
                        bv = better ? v : bv;
                        bj = better ? j : bj;
                    }
                    // reduce over the 16-lane group (val desc, idx asc)
                    #pragma unroll
                    for (int mm = 1; mm <= 8; mm <<= 1) {
                        float ov = __shfl_xor(bv, mm);
                        int   oj = __shfl_xor(bj, mm);
                        bool take = (ov > bv || (ov == bv && oj < bj));
                        bv = take ? ov : bv;
                        bj = take ? oj : bj;
                    }
                    float t9 = tval[row_g][KNEI - 1];
                    int   i9 = tidxs[row_g][KNEI - 1];
                    bool pass = (!done) && (bv > t9 || (bv == t9 && bj < i9));
                    done = done || !pass;
                    if (__all(done)) break;
                    if (pass && (lane & 15) == 0) {
                        int pp = KNEI - 1;
                        tval[row_g][pp] = bv; tidxs[row_g][pp] = bj;
                        while (pp > 0) {
                            float pv = tval[row_g][pp - 1]; int pi = tidxs[row_g][pp - 1];
                            if (bv > pv || (bv == pv && bj < pi)) {
                                tval[row_g][pp] = pv; tidxs[row_g][pp] = pi;
                                tval[row_g][pp - 1] = bv; tidxs[row_g][pp - 1] = bj;
                                --pp;
                            } else break;
                        }
                    }
                    __builtin_amdgcn_wave_barrier();
                    lv = bv; lj = bj;
                }
            }
        }

        // write prefetched step into the other buffer
        if (u < GR_STEPS - 1) {
            #pragma unroll
            for (int q = 0; q < 2; q++) {
                int g = stg_seg * 2 + q;
                *reinterpret_cast<bf16x8*>(&Bl[cur ^ 1][stg_row][(g ^ (stg_row & 7)) * 8]) = pre[q];
            }
        }
        __syncthreads();
    }

    for (int e = tid; e < GR_ROWS * KNEI; e += 512) {
        int r = e / KNEI, m = e % KNEI;
        size_t o = (((size_t)(r0 + r) * GR_CHUNKS) + ch) * KNEI + m;
        tpv[o] = tval[r][m];
        tpi[o] = tidxs[r][m];
    }
}

// ---------------- merge 8 partial top-10 lists per row ----------------
__global__ __launch_bounds__(256) void k_topk_merge(const float* __restrict__ tpv,
        const int* __restrict__ tpi, int* __restrict__ topidx) {
    int r = blockIdx.x * 256 + threadIdx.x;
    int p[GR_CHUNKS];
    #pragma unroll
    for (int c = 0; c < GR_CHUNKS; c++) p[c] = 0;
    #pragma unroll
    for (int m = 0; m < KNEI; m++) {
        float bv = -INFINITY; int bi = 0x7fffffff; int bc = 0;
        #pragma unroll
        for (int c = 0; c < GR_CHUNKS; c++) {
            if (p[c] < KNEI) {
                size_t o = (((size_t)r * GR_CHUNKS) + c) * KNEI + p[c];
                float v = tpv[o];
                int idx = tpi[o];
                if (v > bv || (v == bv && idx < bi)) { bv = v; bi = idx; bc = c; }
            }
        }
        topidx[(size_t)r * KNEI + m] = bi;
        p[bc]++;
    }
}

// ---------------- build symmetric adjacency bitmask ----------------
__global__ void k_set_edges(const int* __restrict__ topidx, unsigned int* __restrict__ mask) {
    int t = blockIdx.x * 256 + threadIdx.x;
    if (t >= NPTS * KNEI) return;
    int i = t / KNEI;
    int j = topidx[t];
    atomicOr(&mask[(size_t)i * (NPTS / 32) + (j >> 5)], 1u << (j & 31));
    atomicOr(&mask[(size_t)j * (NPTS / 32) + (i >> 5)], 1u << (i & 31));
}

// ---------------- degree, inv ----------------
__global__ void k_degree(const unsigned int* __restrict__ mask, float* __restrict__ degf,
                         float* __restrict__ inv) {
    int i = blockIdx.x, lane = threadIdx.x;  // 64 threads
    int c = 0;
    for (int w = lane; w < NPTS / 32; w += 64) c += __popc(mask[(size_t)i * (NPTS / 32) + w]);
    for (int off = 32; off > 0; off >>= 1) c += __shfl_xor(c, off);
    if (lane == 0) {
        float d = (float)c;
        degf[i] = d;
        inv[i] = (c > 0) ? 1.0f / d : 0.0f;
    }
}

// ---------------- bf16x3 MFMA GEMM: C[M,N] = A[M,K] @ B[K,N] ----------------
// A given as hi/lo bf16 [M][K]; B given pre-transposed hi/lo bf16 [N][K].
// (Ahi+Alo)(Bhi+Blo) ~= AhiBhi + AhiBlo + AloBhi  (AloBlo ~ 2^-18, dropped)
__global__ __launch_bounds__(256) void k_gemm_mfma(
    const unsigned short* __restrict__ Ahi, const unsigned short* __restrict__ Alo,
    const unsigned short* __restrict__ BThi, const unsigned short* __restrict__ BTlo,
    float* __restrict__ C, int M, int K, int N)
{
    const int tid = threadIdx.x, lane = tid & 63, wv = tid >> 6;
    const int bx = blockIdx.x, by = blockIdx.y;
    const int arow = by * 64 + wv * 16 + (lane & 15);
    const int koff = (lane >> 4) * 8;

    f32x4 acc[8];
    #pragma unroll
    for (int ct = 0; ct < 8; ct++) acc[ct] = (f32x4){0.f, 0.f, 0.f, 0.f};

    for (int kb = 0; kb < K; kb += 128) {
        bf16x8 ah[4], al[4];
        #pragma unroll
        for (int ksl = 0; ksl < 4; ksl++) {
            ah[ksl] = *reinterpret_cast<const bf16x8*>(Ahi + (size_t)arow * K + kb + ksl * 32 + koff);
            al[ksl] = *reinterpret_cast<const bf16x8*>(Alo + (size_t)arow * K + kb + ksl * 32 + koff);
        }
        #pragma unroll
        for (int ksl = 0; ksl < 4; ksl++) {
            #pragma unroll
            for (int ct = 0; ct < 8; ct++) {
                const int n = bx * 128 + ct * 16 + (lane & 15);
                bf16x8 bh = *reinterpret_cast<const bf16x8*>(BThi + (size_t)n * K + kb + ksl * 32 + koff);
                bf16x8 bl = *reinterpret_cast<const bf16x8*>(BTlo + (size_t)n * K + kb + ksl * 32 + koff);
                acc[ct] = __builtin_amdgcn_mfma_f32_16x16x32_bf16(ah[ksl], bh, acc[ct], 0, 0, 0);
                acc[ct] = __builtin_amdgcn_mfma_f32_16x16x32_bf16(ah[ksl], bl, acc[ct], 0, 0, 0);
                acc[ct] = __builtin_amdgcn_mfma_f32_16x16x32_bf16(al[ksl], bh, acc[ct], 0, 0, 0);
            }
        }
    }
    #pragma unroll
    for (int ct = 0; ct < 8; ct++) {
        const int col = bx * 128 + ct * 16 + (lane & 15);
        #pragma unroll
        for (int r = 0; r < 4; r++) {
            const int row = by * 64 + wv * 16 + (lane >> 4) * 4 + r;
            C[(size_t)row * N + col] = acc[ct][r];
        }
    }
}

// ---------------- column sums of P: colsum[f] = sum_j P[j,f] ----------------
__global__ __launch_bounds__(256) void k_colsum(const float* __restrict__ P, float* __restrict__ colsum, int Fd) {
    int f = blockIdx.x * 256 + threadIdx.x;
    int r0 = blockIdx.y * (NPTS / 64);
    float s = 0.f;
    for (int r = 0; r < NPTS / 64; r++) s += P[(size_t)(r0 + r) * Fd + f];
    atomicAdd(&colsum[f], s);
}

// ---------------- aggregation + skip + bias + activation (dual-mode) ----------------
template <int ACT>
__global__ __launch_bounds__(256) void k_aggregate(const float* __restrict__ P, float* __restrict__ OUT,
        const float* __restrict__ skip, const float* __restrict__ bias,
        const float* __restrict__ inv, const unsigned int* __restrict__ mask,
        const float* __restrict__ colsum, int Fd) {
    __shared__ unsigned short list[LISTCAP];
    __shared__ int cnt_total;
    __shared__ int pos;
    int i = blockIdx.x, tid = threadIdx.x;
    if (tid == 0) { cnt_total = 0; pos = 0; }
    __syncthreads();
    unsigned int w = mask[(size_t)i * (NPTS / 32) + tid];  // 256 words, 256 threads
    atomicAdd(&cnt_total, __popc(w));
    __syncthreads();
    const int deg = cnt_total;
    const bool comp = deg > 4096;
    unsigned int wm = comp ? ~w : w;
    if (comp && tid == (i >> 5)) wm &= ~(1u << (i & 31));   // exclude self from complement
    while (wm) {
        int b = __ffs(wm) - 1;
        wm &= wm - 1;
        int pp = atomicAdd(&pos, 1);
        list[pp] = (unsigned short)(tid * 32 + b);
    }
    __syncthreads();
    const int n = comp ? (NPTS - 1 - deg) : deg;
    const float vinv = inv[i];
    for (int f = tid; f < Fd; f += 256) {
        float s = 0.f;
        for (int q = 0; q < n; q++) s += P[(size_t)list[q] * Fd + f];
        const float pif = P[(size_t)i * Fd + f];
        const float nb = comp ? (colsum[f] - pif - s) : s;
        float o = pif * skip[f] + vinv * nb + bias[f];
        if (ACT == 1) o = (o > 0.f) ? 1.0507009873554805f * o : 0.f;
        OUT[(size_t)i * Fd + f] = o;
    }
}

// ---------------- logits + softmax -> assign ----------------
__global__ void k_assign(const float* __restrict__ emb, const float* __restrict__ Wt,
                         const float* __restrict__ bt, float* __restrict__ assign) {
    int i = blockIdx.x, lane = threadIdx.x;  // 64 threads
    float e[4];
    #pragma unroll
    for (int m = 0; m < 4; m++) e[m] = emb[(size_t)i * FOUT + lane + 64 * m];
    float logit[NCLU];
    #pragma unroll
    for (int c = 0; c < NCLU; c++) {
        float p = 0.f;
        #pragma unroll
        for (int m = 0; m < 4; m++) p = fmaf(e[m], Wt[c * FOUT + lane + 64 * m], p);
        #pragma unroll
        for (int off = 32; off > 0; off >>= 1) p += __shfl_xor(p, off);
        logit[c] = p + bt[c];
    }
    float mx = logit[0];
    #pragma unroll
    for (int c = 1; c < NCLU; c++) mx = fmaxf(mx, logit[c]);
    float sum = 0.f, pr[NCLU];
    #pragma unroll
    for (int c = 0; c < NCLU; c++) { pr[c] = expf(logit[c] - mx); sum += pr[c]; }
    float isum = 1.f / sum;
    if (lane < NCLU) {
        float v = 0.f;
        #pragma unroll
        for (int c = 0; c < NCLU; c++) if (lane == c) v = pr[c];
        assign[(size_t)i * NCLU + lane] = v * isum;
    }
}

// ---------------- stats: colA[c], v[c] = sum_i assign[i,c]*deg[i], Esum = sum deg ----------------
__global__ __launch_bounds__(256) void k_stats(const float* __restrict__ assign,
        const float* __restrict__ degf, float* __restrict__ colA,
        float* __restrict__ vvec, float* __restrict__ Esum) {
    __shared__ float sc[NCLU], sv[NCLU], se;
    int tid = threadIdx.x;
    if (tid < NCLU) { sc[tid] = 0.f; sv[tid] = 0.f; }
    if (tid == 0) se = 0.f;
    __syncthreads();
    int i = blockIdx.x * 256 + tid;
    const float d = degf[i];
    const float* ar = assign + (size_t)i * NCLU;
    float ed = d;
    #pragma unroll
    for (int off = 32; off > 0; off >>= 1) ed += __shfl_xor(ed, off);
    if ((tid & 63) == 0) atomicAdd(&se, ed);
    #pragma unroll
    for (int c = 0; c < NCLU; c++) {
        float a = ar[c];
        float av = a * d;
        #pragma unroll
        for (int off = 32; off > 0; off >>= 1) { a += __shfl_xor(a, off); av += __shfl_xor(av, off); }
        if ((tid & 63) == 0) { atomicAdd(&sc[c], a); atomicAdd(&sv[c], av); }
    }
    __syncthreads();
    if (tid < NCLU) { atomicAdd(&colA[tid], sc[tid]); atomicAdd(&vvec[tid], sv[tid]); }
    if (tid == NCLU) atomicAdd(Esum, se);
}

// ---------------- spectral: Tpart[i] (no atomics) ----------------
__global__ __launch_bounds__(256) void k_spectral(const unsigned int* __restrict__ mask,
        const float* __restrict__ assign, const float* __restrict__ colA,
        float* __restrict__ Tpart) {
    __shared__ unsigned short list[LISTCAP];
    __shared__ int cnt_total;
    __shared__ int pos;
    __shared__ float red[4][NCLU];
    int i = blockIdx.x, tid = threadIdx.x;
    if (tid == 0) { cnt_total = 0; pos = 0; }
    __syncthreads();
    unsigned int w = mask[(size_t)i * (NPTS / 32) + tid];
    atomicAdd(&cnt_total, __popc(w));
    __syncthreads();
    const int deg = cnt_total;
    const bool comp = deg > 4096;
    unsigned int wm = comp ? ~w : w;
    if (comp && tid == (i >> 5)) wm &= ~(1u << (i & 31));
    while (wm) {
        int b = __ffs(wm) - 1;
        wm &= wm - 1;
        int pp = atomicAdd(&pos, 1);
        list[pp] = (unsigned short)(tid * 32 + b);
    }
    __syncthreads();
    const int n = comp ? (NPTS - 1 - deg) : deg;
    float yc[NCLU];
    #pragma unroll
    for (int c = 0; c < NCLU; c++) yc[c] = 0.f;
    for (int q = tid; q < n; q += 256) {
        const float* aj = assign + (size_t)list[q] * NCLU;
        #pragma unroll
        for (int c = 0; c < NCLU; c++) yc[c] += aj[c];
    }
    #pragma unroll
    for (int c = 0; c < NCLU; c++) {
        #pragma unroll
        for (int off = 32; off > 0; off >>= 1) yc[c] += __shfl_xor(yc[c], off);
    }
    int wv = tid >> 6, lane = tid & 63;
    if (lane == 0) {
        #pragma unroll
        for (int c = 0; c < NCLU; c++) red[wv][c] = yc[c];
    }
    __syncthreads();
    if (tid == 0) {
        const float* ai = assign + (size_t)i * NCLU;
        float t = 0.f;
        #pragma unroll
        for (int c = 0; c < NCLU; c++) {
            float y = red[0][c] + red[1][c] + red[2][c] + red[3][c];
            if (comp) y = colA[c] - ai[c] - y;
            t = fmaf(y, ai[c], t);
        }
        Tpart[i] = t;
    }
}

// ---------------- final scalar: reduce Tpart + combine ----------------
__global__ __launch_bounds__(256) void k_final(const float* __restrict__ Tpart,
        const float* __restrict__ v, const float* __restrict__ Esum, float* __restrict__ out) {
    __shared__ float red[256];
    int tid = threadIdx.x;
    float s = 0.f;
    for (int i = tid; i < NPTS; i += 256) s += Tpart[i];
    red[tid] = s; __syncthreads();
    for (int off = 128; off > 0; off >>= 1) {
        if (tid < off) red[tid] += red[tid + off];
        __syncthreads();
    }
    if (tid == 0) {
        float E = *Esum;
        float v2 = 0.f;
        for (int c = 0; c < NCLU; c++) v2 += v[c] * v[c];
        float tr_norm = v2 / (2.f * E);
        out[0] = -(red[0] - tr_norm) / (2.f * E);
    }
}

extern "C" void kernel_launch(void* const* d_in, const int* in_sizes, int n_in,
                              void* d_out, int out_size, void* d_ws, size_t ws_size,
                              hipStream_t stream) {
    const float* x     = (const float*)d_in[0];
    const float* W1    = (const float*)d_in[1];
    const float* b1    = (const float*)d_in[2];
    const float* skip1 = (const float*)d_in[3];
    const float* W2    = (const float*)d_in[4];
    const float* b2    = (const float*)d_in[5];
    const float* skip2 = (const float*)d_in[6];
    const float* Wt    = (const float*)d_in[7];
    const float* bt    = (const float*)d_in[8];

    char* ws = (char*)d_ws;
    float* bufA = (float*)ws;                                      // 16 MB
    float* bufB = (float*)(ws + ((size_t)16 << 20));               // 16 MB
    unsigned int* mask = (unsigned int*)(ws + ((size_t)32 << 20)); // 8 MB bitmask
    unsigned short* xlo = (unsigned short*)(ws + ((size_t)40 << 20)); // 8 MB (lo of x, then lo of h)
    char* p = ws + ((size_t)48 << 20);
    float* sq     = (float*)p; p += NPTS * 4;
    float* degf   = (float*)p; p += NPTS * 4;
    float* inv    = (float*)p; p += NPTS * 4;
    int*   topidx = (int*)p;   p += (size_t)NPTS * KNEI * 4;
    float* assign = (float*)p; p += (size_t)NPTS * NCLU * 4;
    float* Tpart  = (float*)p; p += NPTS * 4;
    // contiguous zero-region: Esum, vvec[10], colA[10], colsum1[512], colsum2[256]
    float* Esum    = (float*)p; p += 4;
    float* vvec    = (float*)p; p += NCLU * 4;
    float* colA    = (float*)p; p += NCLU * 4;
    float* colsum1 = (float*)p; p += FHID * 4;
    float* colsum2 = (float*)p; p += FOUT * 4;
    unsigned short* WT1hi = (unsigned short*)p; p += (size_t)FHID * FIN * 2;   // [512][512]
    unsigned short* WT1lo = (unsigned short*)p; p += (size_t)FHID * FIN * 2;
    unsigned short* WT2hi = (unsigned short*)p; p += (size_t)FOUT * FHID * 2;  // [256][512]
    unsigned short* WT2lo = (unsigned short*)p; p += (size_t)FOUT * FHID * 2;

    // xb (bf16 hi of x, 8MB) aliases bufA[0:8MB]: dead before gemm1 writes bufB/aggregate writes bufA.
    unsigned short* xb = (unsigned short*)bufA;
    // tpv/tpi alias bufB: consumed by k_topk_merge before gemm1 overwrites bufB.
    float* tpv = (float*)bufB;
    int*   tpi = (int*)((char*)bufB + ((size_t)4 << 20));
    // layer-2 split targets: h_hi -> bufB[0:8MB] (P1 dead), h_lo -> xlo; P2 -> bufB[8:16MB]
    unsigned short* hhi = (unsigned short*)bufB;
    float* P2 = bufB + ((size_t)2 << 20);   // 8 MB offset in floats

    hipMemsetAsync(mask, 0, (size_t)NPTS * (NPTS / 32) * 4, stream); // 8 MB
    hipMemsetAsync(Esum, 0, (1 + 2 * NCLU + FHID + FOUT) * sizeof(float), stream);

    k_sumsq<<<NPTS, 256, 0, stream>>>(x, sq);
    k_split<<<(NPTS * FIN / 4) / 256, 256, 0, stream>>>(x, xb, xlo);
    k_wtrans<<<dim3(FHID / 32, FIN / 32), 256, 0, stream>>>(W1, WT1hi, WT1lo, FIN, FHID);
    k_wtrans<<<dim3(FOUT / 32, FHID / 32), 256, 0, stream>>>(W2, WT2hi, WT2lo, FHID, FOUT);

    k_gram_topk<<<(NPTS / GR_ROWS) * GR_CHUNKS, 512, 0, stream>>>(xb, sq, tpv, tpi);
    k_topk_merge<<<NPTS / 256, 256, 0, stream>>>(tpv, tpi, topidx);
    k_set_edges<<<(NPTS * KNEI + 255) / 256, 256, 0, stream>>>(topidx, mask);
    k_degree<<<NPTS, 64, 0, stream>>>(mask, degf, inv);

    // layer 1: P1 = x @ W1 (bf16x3 MFMA) -> bufB ; h = act1(...) -> bufA
    k_gemm_mfma<<<dim3(FHID / 128, NPTS / 64), 256, 0, stream>>>(xb, xlo, WT1hi, WT1lo, bufB, NPTS, FIN, FHID);
    k_colsum<<<dim3(FHID / 256, 64), 256, 0, stream>>>(bufB, colsum1, FHID);
    k_aggregate<1><<<NPTS, 256, 0, stream>>>(bufB, bufA, skip1, b1, inv, mask, colsum1, FHID);

    // layer 2: split h; P2 = h @ W2 -> bufB[8:16MB] ; emb -> bufA
    k_split<<<(NPTS * FHID / 4) / 256, 256, 0, stream>>>(bufA, hhi, xlo);
    k_gemm_mfma<<<dim3(FOUT / 128, NPTS / 64), 256, 0, stream>>>(hhi, xlo, WT2hi, WT2lo, P2, NPTS, FHID, FOUT);
    k_colsum<<<dim3(FOUT / 256, 64), 256, 0, stream>>>(P2, colsum2, FOUT);
    k_aggregate<0><<<NPTS, 256, 0, stream>>>(P2, bufA, skip2, b2, inv, mask, colsum2, FOUT);

    k_assign<<<NPTS, 64, 0, stream>>>(bufA, Wt, bt, assign);
    k_stats<<<NPTS / 256, 256, 0, stream>>>(assign, degf, colA, vvec, Esum);
    k_spectral<<<NPTS, 256, 0, stream>>>(mask, assign, colA, Tpart);
    k_final<<<1, 256, 0, stream>>>(Tpart, vvec, Esum, (float*)d_out);
}